// Round 1
// baseline (222.126 us; speedup 1.0000x reference)
//
#include <hip/hip_runtime.h>
#include <hip/hip_bf16.h>

#define BB 2
#define SS 2048
#define DD 768
#define HH 12
#define DHH 64
#define WIN 128
#define MM (BB*SS)

typedef __attribute__((ext_vector_type(8))) short bfrag;
typedef __attribute__((ext_vector_type(4))) float f32x4;

__device__ inline unsigned short f2bf(float f) {
    union { __hip_bfloat16 h; unsigned short u; } cv;
    cv.h = __float2bfloat16(f);
    return cv.u;
}

// ---------------- Kernel 1: fused QKV projection + bias + RoPE ----------------
// grid (MM/64, H, 3): 64x64 tile of one head's projection. which: 0=q,1=k,2=v.
// q,k out: (B,H,S,DH) bf16. v out: (B,H,DH,S) bf16 (transposed for PV B-frags).
__global__ __launch_bounds__(256) void qkv_rope_kernel(
    const float* __restrict__ Xq, const float* __restrict__ Xk, const float* __restrict__ Xv,
    const float* __restrict__ Wq, const float* __restrict__ Wk, const float* __restrict__ Wv,
    const float* __restrict__ bq, const float* __restrict__ bk, const float* __restrict__ bv,
    unsigned short* __restrict__ qo, unsigned short* __restrict__ ko, unsigned short* __restrict__ vo)
{
    const int mt0   = blockIdx.x * 64;
    const int h     = blockIdx.y;
    const int which = blockIdx.z;
    const float* X    = which == 0 ? Xq : (which == 1 ? Xk : Xv);
    const float* W    = (which == 0 ? Wq : (which == 1 ? Wk : Wv)) + (size_t)h * DD * DHH;
    const float* bias = (which == 0 ? bq : (which == 1 ? bk : bv)) + h * DHH;

    __shared__ unsigned short Xs[64 * 40];   // X tile, stride 40 (pad)
    __shared__ unsigned short Ws[64 * 40];   // W tile transposed: Ws[kdh][dlocal]
    __shared__ float Cs[64 * 65];            // fp32 result tile for RoPE pairing

    const int t = threadIdx.x;
    const int w = t >> 6, lane = t & 63;
    const int l16 = lane & 15, quad = lane >> 4;

    f32x4 acc[4] = {};
    for (int kk = 0; kk < DD; kk += 32) {
        { // X tile 64x32: thread loads 8 consecutive fp32
            int row = t >> 2, c = (t & 3) * 8;
            const float4* p = reinterpret_cast<const float4*>(X + (size_t)(mt0 + row) * DD + kk + c);
            float4 v0 = p[0], v1 = p[1];
            unsigned short* dst = &Xs[row * 40 + c];
            dst[0]=f2bf(v0.x); dst[1]=f2bf(v0.y); dst[2]=f2bf(v0.z); dst[3]=f2bf(v0.w);
            dst[4]=f2bf(v1.x); dst[5]=f2bf(v1.y); dst[6]=f2bf(v1.z); dst[7]=f2bf(v1.w);
        }
        { // W tile (32 d x 64 kdh), stored transposed Ws[kdh][d]
            int dlocal = t >> 3, kdh0 = (t & 7) * 8;
            const float4* p = reinterpret_cast<const float4*>(W + (size_t)(kk + dlocal) * DHH + kdh0);
            float4 v0 = p[0], v1 = p[1];
            float vv[8] = {v0.x, v0.y, v0.z, v0.w, v1.x, v1.y, v1.z, v1.w};
            #pragma unroll
            for (int i = 0; i < 8; i++) Ws[(kdh0 + i) * 40 + dlocal] = f2bf(vv[i]);
        }
        __syncthreads();
        bfrag a = *reinterpret_cast<const bfrag*>(&Xs[(16 * w + l16) * 40 + quad * 8]);
        #pragma unroll
        for (int j = 0; j < 4; j++) {
            bfrag bf = *reinterpret_cast<const bfrag*>(&Ws[(16 * j + l16) * 40 + quad * 8]);
            acc[j] = __builtin_amdgcn_mfma_f32_16x16x32_bf16(a, bf, acc[j], 0, 0, 0);
        }
        __syncthreads();
    }
    // stage result tile to LDS fp32 (need cross-lane pairs for RoPE / transpose for v)
    #pragma unroll
    for (int j = 0; j < 4; j++)
        #pragma unroll
        for (int r = 0; r < 4; r++)
            Cs[(16 * w + quad * 4 + r) * 65 + 16 * j + l16] = acc[j][r];
    __syncthreads();

    const int b  = mt0 / SS;   // block-uniform (64 | SS)
    const int p0 = mt0 % SS;
    if (which < 2) {
        unsigned short* out = (which == 0) ? qo : ko;
        size_t base = ((size_t)(b * HH + h) * SS + p0) * DHH;
        for (int e = t; e < 4096; e += 256) {
            int r = e >> 6, c = e & 63;
            float val  = Cs[r * 65 + c] + bias[c];
            float pair = Cs[r * 65 + (c ^ 32)] + bias[c ^ 32];
            float rot  = (c < 32) ? -pair : pair;
            int i2 = c & 31;
            // 10000^(-i2/32) = 2^(-i2/32 * log2(10000))
            float inv_freq = exp2f(-(float)i2 * (13.287712379549449f / 32.0f));
            float ang = (float)(p0 + r) * inv_freq;
            float sv, cv2;
            sincosf(ang, &sv, &cv2);
            out[base + (size_t)r * DHH + c] = f2bf(val * cv2 + rot * sv);
        }
    } else {
        size_t base = ((size_t)(b * HH + h) * DHH) * SS + p0;
        for (int e = t; e < 4096; e += 256) {
            int d = e >> 6, r = e & 63;   // consecutive t -> consecutive position r (coalesced)
            float val = Cs[r * 65 + d] + bias[d];
            vo[base + (size_t)d * SS + r] = f2bf(val);
        }
    }
}

// ---------------- Kernel 2: sliding-window attention ----------------
// grid (S/64, H, B). 64 q-rows x 192 keys (full window in-tile; exact softmax).
__global__ __launch_bounds__(256) void attn_kernel(
    const unsigned short* __restrict__ q,
    const unsigned short* __restrict__ k,
    const unsigned short* __restrict__ v,
    unsigned short* __restrict__ z)
{
    const int qb = blockIdx.x * 64;
    const int h  = blockIdx.y;
    const int b  = blockIdx.z;
    const int kb = qb - WIN;   // first key index (may be negative -> masked)

    __shared__ unsigned short QK[64 * 72 + 192 * 72]; // Q (stride 72) then K (stride 72)
    __shared__ unsigned short Ps[64 * 200];           // P row-major, stride 200
    unsigned short* Qs = QK;
    unsigned short* Ks = QK + 64 * 72;
    unsigned short* Vt = QK;                          // aliases Q/K after QK^T phase (needs 64*200 <= 18432)

    const int t = threadIdx.x;
    const int w = t >> 6, lane = t & 63;
    const int l16 = lane & 15, quad = lane >> 4;

    const size_t qkbase = ((size_t)(b * HH + h) * SS) * DHH;
    #pragma unroll
    for (int i = 0; i < 2; i++) {  // Q: 64 rows
        int chunk = i * 256 + t;
        int row = chunk >> 3, c0 = (chunk & 7) * 8;
        bfrag val = *reinterpret_cast<const bfrag*>(q + qkbase + (size_t)(qb + row) * DHH + c0);
        *reinterpret_cast<bfrag*>(&Qs[row * 72 + c0]) = val;
    }
    #pragma unroll
    for (int i = 0; i < 6; i++) {  // K: 192 rows, clamp OOB (masked later)
        int chunk = i * 256 + t;
        int row = chunk >> 3, c0 = (chunk & 7) * 8;
        int src = kb + row; if (src < 0) src = 0;
        bfrag val = *reinterpret_cast<const bfrag*>(k + qkbase + (size_t)src * DHH + c0);
        *reinterpret_cast<bfrag*>(&Ks[row * 72 + c0]) = val;
    }
    __syncthreads();

    f32x4 sacc[12] = {};
    #pragma unroll
    for (int kk = 0; kk < 64; kk += 32) {
        bfrag a = *reinterpret_cast<const bfrag*>(&Qs[(16 * w + l16) * 72 + kk + quad * 8]);
        #pragma unroll
        for (int mt = 0; mt < 12; mt++) {
            bfrag bf = *reinterpret_cast<const bfrag*>(&Ks[(16 * mt + l16) * 72 + kk + quad * 8]);
            sacc[mt] = __builtin_amdgcn_mfma_f32_16x16x32_bf16(a, bf, sacc[mt], 0, 0, 0);
        }
    }

    // mask + scale; rows owned by this lane: 16w + quad*4 + r
    float mx[4] = {-3e38f, -3e38f, -3e38f, -3e38f};
    #pragma unroll
    for (int mt = 0; mt < 12; mt++)
        #pragma unroll
        for (int r = 0; r < 4; r++) {
            int row = 16 * w + quad * 4 + r;
            int c = 16 * mt + l16;
            // valid keys for query i=qb+row: c in (row, row+128], and key index >= 0
            bool valid = (c > row) && (c <= row + WIN) && (kb + c >= 0);
            float s = valid ? sacc[mt][r] * 0.125f : -3e38f;
            sacc[mt][r] = s;
            mx[r] = fmaxf(mx[r], s);
        }
    #pragma unroll
    for (int off = 1; off < 16; off <<= 1)
        #pragma unroll
        for (int r = 0; r < 4; r++) mx[r] = fmaxf(mx[r], __shfl_xor(mx[r], off, 64));
    float sum[4] = {0.f, 0.f, 0.f, 0.f};
    #pragma unroll
    for (int mt = 0; mt < 12; mt++)
        #pragma unroll
        for (int r = 0; r < 4; r++) {
            float p = __expf(sacc[mt][r] - mx[r]);
            sacc[mt][r] = p;
            sum[r] += p;
        }
    #pragma unroll
    for (int off = 1; off < 16; off <<= 1)
        #pragma unroll
        for (int r = 0; r < 4; r++) sum[r] += __shfl_xor(sum[r], off, 64);
    float inv[4];
    #pragma unroll
    for (int r = 0; r < 4; r++) inv[r] = 1.0f / sum[r];

    // P -> LDS (row-major, A-operand-friendly)
    #pragma unroll
    for (int mt = 0; mt < 12; mt++)
        #pragma unroll
        for (int r = 0; r < 4; r++)
            Ps[(16 * w + quad * 4 + r) * 200 + 16 * mt + l16] = f2bf(sacc[mt][r] * inv[r]);
    __syncthreads();  // all Q/K reads done -> safe to overwrite with Vt

    // load V^T tile: Vt[d][c] = V[key kb+c][d]; v stored (B,H,DH,S)
    const size_t vbase = ((size_t)(b * HH + h) * DHH) * SS;
    if (kb >= 0) {
        #pragma unroll
        for (int i = 0; i < 6; i++) {
            int chunk = i * 256 + t;           // 64 rows x 24 chunks
            int d = chunk / 24, c0 = (chunk % 24) * 8;
            bfrag val = *reinterpret_cast<const bfrag*>(v + vbase + (size_t)d * SS + kb + c0);
            *reinterpret_cast<bfrag*>(&Vt[d * 200 + c0]) = val;
        }
    } else {
        for (int i = 0; i < 6; i++) {
            int chunk = i * 256 + t;
            int d = chunk / 24, c0 = (chunk % 24) * 8;
            unsigned short tmp[8];
            for (int j2 = 0; j2 < 8; j2++) {
                int src = kb + c0 + j2; if (src < 0) src = 0;
                tmp[j2] = v[vbase + (size_t)d * SS + src];
            }
            for (int j2 = 0; j2 < 8; j2++) Vt[d * 200 + c0 + j2] = tmp[j2];
        }
    }
    __syncthreads();

    f32x4 zacc[4] = {};
    #pragma unroll
    for (int c0 = 0; c0 < 192; c0 += 32) {
        bfrag a = *reinterpret_cast<const bfrag*>(&Ps[(16 * w + l16) * 200 + c0 + quad * 8]);
        #pragma unroll
        for (int nt = 0; nt < 4; nt++) {
            bfrag bf = *reinterpret_cast<const bfrag*>(&Vt[(16 * nt + l16) * 200 + c0 + quad * 8]);
            zacc[nt] = __builtin_amdgcn_mfma_f32_16x16x32_bf16(a, bf, zacc[nt], 0, 0, 0);
        }
    }
    // z: (B,S,H*DH) bf16
    #pragma unroll
    for (int nt = 0; nt < 4; nt++)
        #pragma unroll
        for (int r = 0; r < 4; r++) {
            int row = 16 * w + quad * 4 + r;
            int d = 16 * nt + l16;
            z[((size_t)(b * SS + qb + row)) * (HH * DHH) + h * DHH + d] = f2bf(zacc[nt][r]);
        }
}

// ---------------- Kernel 3: output projection ----------------
// out(4096x768) = Z(4096x768 bf16) @ Wo(768x768) + bo ; fp32 out
__global__ __launch_bounds__(256) void out_proj_kernel(
    const unsigned short* __restrict__ Z,
    const float* __restrict__ Wo,
    const float* __restrict__ bo,
    float* __restrict__ out)
{
    const int mt0 = blockIdx.x * 64;
    const int n0  = blockIdx.y * 64;
    __shared__ unsigned short As[64 * 40];
    __shared__ unsigned short Bs[64 * 40];  // Bt[n][k]
    const int t = threadIdx.x, w = t >> 6, lane = t & 63;
    const int l16 = lane & 15, quad = lane >> 4;

    f32x4 acc[4] = {};
    for (int kk = 0; kk < DD; kk += 32) {
        {
            int row = t >> 2, c = (t & 3) * 8;
            bfrag val = *reinterpret_cast<const bfrag*>(Z + (size_t)(mt0 + row) * DD + kk + c);
            *reinterpret_cast<bfrag*>(&As[row * 40 + c]) = val;
        }
        {
            int klocal = t >> 3, c8 = (t & 7) * 8;
            const float4* p = reinterpret_cast<const float4*>(Wo + (size_t)(kk + klocal) * DD + n0 + c8);
            float4 v0 = p[0], v1 = p[1];
            float vv[8] = {v0.x, v0.y, v0.z, v0.w, v1.x, v1.y, v1.z, v1.w};
            #pragma unroll
            for (int i = 0; i < 8; i++) Bs[(c8 + i) * 40 + klocal] = f2bf(vv[i]);
        }
        __syncthreads();
        bfrag a = *reinterpret_cast<const bfrag*>(&As[(16 * w + l16) * 40 + quad * 8]);
        #pragma unroll
        for (int j = 0; j < 4; j++) {
            bfrag bf = *reinterpret_cast<const bfrag*>(&Bs[(16 * j + l16) * 40 + quad * 8]);
            acc[j] = __builtin_amdgcn_mfma_f32_16x16x32_bf16(a, bf, acc[j], 0, 0, 0);
        }
        __syncthreads();
    }
    #pragma unroll
    for (int j = 0; j < 4; j++)
        #pragma unroll
        for (int r = 0; r < 4; r++) {
            int row = 16 * w + quad * 4 + r, col = n0 + 16 * j + l16;
            out[(size_t)(mt0 + row) * DD + col] = acc[j][r] + bo[col];
        }
}

extern "C" void kernel_launch(void* const* d_in, const int* in_sizes, int n_in,
                              void* d_out, int out_size, void* d_ws, size_t ws_size,
                              hipStream_t stream) {
    const float* Xq = (const float*)d_in[0];
    const float* Xk = (const float*)d_in[1];
    const float* Xv = (const float*)d_in[2];
    const float* Wq = (const float*)d_in[3];
    const float* Wk = (const float*)d_in[4];
    const float* Wv = (const float*)d_in[5];
    const float* Wo = (const float*)d_in[6];
    const float* bq = (const float*)d_in[7];
    const float* bk = (const float*)d_in[8];
    const float* bv = (const float*)d_in[9];
    const float* bo = (const float*)d_in[10];
    float* out = (float*)d_out;

    const size_t seg = (size_t)BB * HH * SS * DHH;  // 3,145,728 elems
    unsigned short* q = (unsigned short*)d_ws;
    unsigned short* k = q + seg;
    unsigned short* v = k + seg;
    unsigned short* z = v + seg;

    qkv_rope_kernel<<<dim3(MM / 64, HH, 3), 256, 0, stream>>>(Xq, Xk, Xv, Wq, Wk, Wv, bq, bk, bv, q, k, v);
    attn_kernel<<<dim3(SS / 64, HH, BB), 256, 0, stream>>>(q, k, v, z);
    out_proj_kernel<<<dim3(MM / 64, DD / 64), 256, 0, stream>>>(z, Wo, bo, out);
}

// Round 2
// 189.701 us; speedup vs baseline: 1.1709x; 1.1709x over previous
//
#include <hip/hip_runtime.h>
#include <hip/hip_bf16.h>

#define BB 2
#define SS 2048
#define DD 768
#define HH 12
#define DHH 64
#define WIN 128
#define MM (BB*SS)

typedef __attribute__((ext_vector_type(8))) short bfrag;
typedef __attribute__((ext_vector_type(4))) float f32x4;

#define AS3(p) ((__attribute__((address_space(3))) void*)(p))
#define AS1(p) ((const __attribute__((address_space(1))) void*)(p))

__device__ inline unsigned short f2bf(float f) {
    union { __hip_bfloat16 h; unsigned short u; } cv;
    cv.h = __float2bfloat16(f);
    return cv.u;
}

// ---------------- Kernel 0: pack weights (transpose to B^T bf16) + rope table ----
// blocks [0,432): W_{Q,K,V} (H,D,DH) -> Wt[proj][h*64+dh][d]
// blocks [432,576): W_O (H*DH, D) -> Wot[d][h*64+dh]
// blocks [576,832): rope table float2(sin,cos)[p][i2]
__global__ __launch_bounds__(256) void pack_kernel(
    const float* __restrict__ Wq, const float* __restrict__ Wk, const float* __restrict__ Wv,
    const float* __restrict__ Wo,
    unsigned short* __restrict__ Wt, unsigned short* __restrict__ Wot,
    float2* __restrict__ rope)
{
    __shared__ float T[64][65];
    const int bid = blockIdx.x, t = threadIdx.x;
    if (bid < 432) {
        int proj = bid / 144, rem = bid % 144;
        int h = rem / 12, d0 = (rem % 12) * 64;
        const float* src = (proj == 0 ? Wq : (proj == 1 ? Wk : Wv)) + (size_t)h * DD * DHH;
        int row = t >> 2, c0 = (t & 3) * 16;
        const float4* p4 = reinterpret_cast<const float4*>(src + (size_t)(d0 + row) * DHH + c0);
        float4 x0 = p4[0], x1 = p4[1], x2 = p4[2], x3 = p4[3];
        float* tr = &T[row][c0];
        tr[0]=x0.x; tr[1]=x0.y; tr[2]=x0.z; tr[3]=x0.w;
        tr[4]=x1.x; tr[5]=x1.y; tr[6]=x1.z; tr[7]=x1.w;
        tr[8]=x2.x; tr[9]=x2.y; tr[10]=x2.z; tr[11]=x2.w;
        tr[12]=x3.x; tr[13]=x3.y; tr[14]=x3.z; tr[15]=x3.w;
        __syncthreads();
        int dh = t >> 2;
        unsigned short tmp[16];
        #pragma unroll
        for (int j = 0; j < 16; j++) tmp[j] = f2bf(T[c0 + j][dh]);
        unsigned short* dst = Wt + (size_t)proj * DD * DD + (size_t)(h * 64 + dh) * DD + d0 + c0;
        *reinterpret_cast<bfrag*>(dst)     = *reinterpret_cast<bfrag*>(tmp);
        *reinterpret_cast<bfrag*>(dst + 8) = *reinterpret_cast<bfrag*>(tmp + 8);
    } else if (bid < 576) {
        int id2 = bid - 432;
        int k0 = (id2 / 12) * 64, n0 = (id2 % 12) * 64;
        int row = t >> 2, c0 = (t & 3) * 16;
        const float4* p4 = reinterpret_cast<const float4*>(Wo + (size_t)(k0 + row) * DD + n0 + c0);
        float4 x0 = p4[0], x1 = p4[1], x2 = p4[2], x3 = p4[3];
        float* tr = &T[row][c0];
        tr[0]=x0.x; tr[1]=x0.y; tr[2]=x0.z; tr[3]=x0.w;
        tr[4]=x1.x; tr[5]=x1.y; tr[6]=x1.z; tr[7]=x1.w;
        tr[8]=x2.x; tr[9]=x2.y; tr[10]=x2.z; tr[11]=x2.w;
        tr[12]=x3.x; tr[13]=x3.y; tr[14]=x3.z; tr[15]=x3.w;
        __syncthreads();
        int nr = t >> 2;
        unsigned short tmp[16];
        #pragma unroll
        for (int j = 0; j < 16; j++) tmp[j] = f2bf(T[c0 + j][nr]);
        unsigned short* dst = Wot + (size_t)(n0 + nr) * DD + k0 + c0;
        *reinterpret_cast<bfrag*>(dst)     = *reinterpret_cast<bfrag*>(tmp);
        *reinterpret_cast<bfrag*>(dst + 8) = *reinterpret_cast<bfrag*>(tmp + 8);
    } else {
        int idx = (bid - 576) * 256 + t;   // 65536 entries: p in [0,2048), i2 in [0,32)
        int p = idx >> 5, i2 = idx & 31;
        float inv_freq = exp2f(-(float)i2 * (13.287712379549449f / 32.0f));
        float s, c;
        sincosf((float)p * inv_freq, &s, &c);
        rope[idx] = make_float2(s, c);
    }
}

// ---------------- Kernel 1: QKV projection GEMM + bias + RoPE ----------------
// grid (32, 6, 3): 128x128 tile. A: fp32 X converted in-register. B: Wt via DMA.
// q,k out (B,H,S,DH) bf16; v out (B,H,DH,S) bf16.
__global__ __launch_bounds__(256) void qkv_gemm_kernel(
    const float* __restrict__ Xq, const float* __restrict__ Xk, const float* __restrict__ Xv,
    const unsigned short* __restrict__ Wt,
    const float* __restrict__ bq, const float* __restrict__ bk, const float* __restrict__ bv,
    const float2* __restrict__ rope,
    unsigned short* __restrict__ qo, unsigned short* __restrict__ ko, unsigned short* __restrict__ vo)
{
    const int mt0  = blockIdx.x * 128;
    const int n0   = blockIdx.y * 128;
    const int proj = blockIdx.z;
    const float* X = proj == 0 ? Xq : (proj == 1 ? Xk : Xv);
    const unsigned short* W = Wt + (size_t)proj * DD * DD;
    const float* bias = proj == 0 ? bq : (proj == 1 ? bk : bv);

    __shared__ unsigned short smem[128 * 140];  // 35840 B; As/Bs in first 16KB, Ct aliases all
    unsigned short* As = smem;
    unsigned short* Bs = smem + 4096;

    const int t = threadIdx.x;
    const int l = t & 63, w4 = t >> 6;
    const int l16 = l & 15, quad = l >> 4;
    const int wr = w4 >> 1, wc = w4 & 1;
    const int swz = (l16 >> 1) & 3;

    f32x4 acc[16] = {};

    const int arow = t >> 1, ac0 = (t & 1) * 16;
    const int as_ = (arow >> 1) & 3;
    const int ak8 = ac0 >> 3;   // 0 or 2
    const float* Xrow = X + (size_t)(mt0 + arow) * DD + ac0;

    for (int k0 = 0; k0 < DD; k0 += 32) {
        // B tile via async DMA (swizzled source so ds_read is 2-way max)
        #pragma unroll
        for (int j = 0; j < 2; j++) {
            int eoff = (w4 * 2 + j) * 512;
            int e = eoff + l * 8;
            int row = e >> 5, cs = (e & 31) >> 3;
            int k8 = cs ^ ((row >> 1) & 3);
            __builtin_amdgcn_global_load_lds(
                AS1(W + (size_t)(n0 + row) * DD + k0 + k8 * 8),
                AS3(Bs + eoff), 16, 0, 0);
        }
        // A tile: 16 fp32 -> 16 bf16 -> two swizzled b128 writes
        {
            const float4* p4 = reinterpret_cast<const float4*>(Xrow + k0);
            float4 a0 = p4[0], a1 = p4[1], a2 = p4[2], a3 = p4[3];
            unsigned short u[16];
            u[0]=f2bf(a0.x); u[1]=f2bf(a0.y); u[2]=f2bf(a0.z); u[3]=f2bf(a0.w);
            u[4]=f2bf(a1.x); u[5]=f2bf(a1.y); u[6]=f2bf(a1.z); u[7]=f2bf(a1.w);
            u[8]=f2bf(a2.x); u[9]=f2bf(a2.y); u[10]=f2bf(a2.z); u[11]=f2bf(a2.w);
            u[12]=f2bf(a3.x); u[13]=f2bf(a3.y); u[14]=f2bf(a3.z); u[15]=f2bf(a3.w);
            *reinterpret_cast<bfrag*>(&As[arow * 32 + ((ak8 ^ as_) * 8)])       = *reinterpret_cast<bfrag*>(u);
            *reinterpret_cast<bfrag*>(&As[arow * 32 + (((ak8 + 1) ^ as_) * 8)]) = *reinterpret_cast<bfrag*>(u + 8);
        }
        __syncthreads();
        bfrag af[4], bg[4];
        #pragma unroll
        for (int mi = 0; mi < 4; mi++)
            af[mi] = *reinterpret_cast<const bfrag*>(&As[(wr * 64 + mi * 16 + l16) * 32 + ((quad ^ swz) * 8)]);
        #pragma unroll
        for (int ni = 0; ni < 4; ni++)
            bg[ni] = *reinterpret_cast<const bfrag*>(&Bs[(wc * 64 + ni * 16 + l16) * 32 + ((quad ^ swz) * 8)]);
        #pragma unroll
        for (int mi = 0; mi < 4; mi++)
            #pragma unroll
            for (int ni = 0; ni < 4; ni++)
                acc[mi * 4 + ni] = __builtin_amdgcn_mfma_f32_16x16x32_bf16(af[mi], bg[ni], acc[mi * 4 + ni], 0, 0, 0);
        __syncthreads();
    }

    unsigned short* Ct = smem;   // stride 140
    const int b = mt0 >> 11;
    if (proj < 2) {
        // bias + RoPE in registers (pair dh^32 = microtile ni^2, same lane)
        #pragma unroll
        for (int ni = 0; ni < 4; ni++) {
            int nloc = wc * 64 + ni * 16 + l16;
            int n = n0 + nloc;
            int dh = n & 63;
            float bv0 = bias[n];
            float bv1 = bias[n ^ 32];
            float sgn = (dh & 32) ? 1.0f : -1.0f;
            const float2* rp = rope + (dh & 31);
            #pragma unroll
            for (int mi = 0; mi < 4; mi++)
                #pragma unroll
                for (int r = 0; r < 4; r++) {
                    int ploc = wr * 64 + mi * 16 + quad * 4 + r;
                    int p = (mt0 + ploc) & (SS - 1);
                    float2 sc = rp[p << 5];
                    float val = acc[mi * 4 + ni][r] + bv0;
                    float pr  = acc[mi * 4 + (ni ^ 2)][r] + bv1;
                    Ct[ploc * 140 + nloc] = f2bf(val * sc.y + sgn * pr * sc.x);
                }
        }
        __syncthreads();
        unsigned short* dst = (proj == 0) ? qo : ko;
        #pragma unroll
        for (int jj = 0; jj < 8; jj++) {
            int id = jj * 256 + t;
            int row = id >> 4, c = (id & 15) * 8;
            int n = n0 + c, h = n >> 6, dh = n & 63;
            int p = (mt0 + row) & (SS - 1);
            bfrag vv = *reinterpret_cast<const bfrag*>(&Ct[row * 140 + c]);
            *reinterpret_cast<bfrag*>(dst + (((size_t)(b * HH + h) * SS + p) << 6) + dh) = vv;
        }
    } else {
        // bias only; store transposed (B,H,DH,S)
        #pragma unroll
        for (int ni = 0; ni < 4; ni++) {
            int nloc = wc * 64 + ni * 16 + l16;
            float bv0 = bias[n0 + nloc];
            #pragma unroll
            for (int mi = 0; mi < 4; mi++)
                #pragma unroll
                for (int r = 0; r < 4; r++) {
                    int ploc = wr * 64 + mi * 16 + quad * 4 + r;
                    Ct[nloc * 140 + ploc] = f2bf(acc[mi * 4 + ni][r] + bv0);
                }
        }
        __syncthreads();
        int p0 = mt0 & (SS - 1);
        #pragma unroll
        for (int jj = 0; jj < 8; jj++) {
            int id = jj * 256 + t;
            int row = id >> 4, c = (id & 15) * 8;   // row = n-local, c = position chunk
            int n = n0 + row, h = n >> 6, dh = n & 63;
            bfrag vv = *reinterpret_cast<const bfrag*>(&Ct[row * 140 + c]);
            *reinterpret_cast<bfrag*>(vo + (((size_t)(b * HH + h) * DHH + dh) << 11) + p0 + c) = vv;
        }
    }
}

// ---------------- Kernel 2: sliding-window attention (unchanged, verified) ------
__global__ __launch_bounds__(256) void attn_kernel(
    const unsigned short* __restrict__ q,
    const unsigned short* __restrict__ k,
    const unsigned short* __restrict__ v,
    unsigned short* __restrict__ z)
{
    const int qb = blockIdx.x * 64;
    const int h  = blockIdx.y;
    const int b  = blockIdx.z;
    const int kb = qb - WIN;

    __shared__ unsigned short QK[64 * 72 + 192 * 72];
    __shared__ unsigned short Ps[64 * 200];
    unsigned short* Qs = QK;
    unsigned short* Ks = QK + 64 * 72;
    unsigned short* Vt = QK;

    const int t = threadIdx.x;
    const int w = t >> 6, lane = t & 63;
    const int l16 = lane & 15, quad = lane >> 4;

    const size_t qkbase = ((size_t)(b * HH + h) * SS) * DHH;
    #pragma unroll
    for (int i = 0; i < 2; i++) {
        int chunk = i * 256 + t;
        int row = chunk >> 3, c0 = (chunk & 7) * 8;
        bfrag val = *reinterpret_cast<const bfrag*>(q + qkbase + (size_t)(qb + row) * DHH + c0);
        *reinterpret_cast<bfrag*>(&Qs[row * 72 + c0]) = val;
    }
    #pragma unroll
    for (int i = 0; i < 6; i++) {
        int chunk = i * 256 + t;
        int row = chunk >> 3, c0 = (chunk & 7) * 8;
        int src = kb + row; if (src < 0) src = 0;
        bfrag val = *reinterpret_cast<const bfrag*>(k + qkbase + (size_t)src * DHH + c0);
        *reinterpret_cast<bfrag*>(&Ks[row * 72 + c0]) = val;
    }
    __syncthreads();

    f32x4 sacc[12] = {};
    #pragma unroll
    for (int kk = 0; kk < 64; kk += 32) {
        bfrag a = *reinterpret_cast<const bfrag*>(&Qs[(16 * w + l16) * 72 + kk + quad * 8]);
        #pragma unroll
        for (int mt = 0; mt < 12; mt++) {
            bfrag bf = *reinterpret_cast<const bfrag*>(&Ks[(16 * mt + l16) * 72 + kk + quad * 8]);
            sacc[mt] = __builtin_amdgcn_mfma_f32_16x16x32_bf16(a, bf, sacc[mt], 0, 0, 0);
        }
    }

    float mx[4] = {-3e38f, -3e38f, -3e38f, -3e38f};
    #pragma unroll
    for (int mt = 0; mt < 12; mt++)
        #pragma unroll
        for (int r = 0; r < 4; r++) {
            int row = 16 * w + quad * 4 + r;
            int c = 16 * mt + l16;
            bool valid = (c > row) && (c <= row + WIN) && (kb + c >= 0);
            float s = valid ? sacc[mt][r] * 0.125f : -3e38f;
            sacc[mt][r] = s;
            mx[r] = fmaxf(mx[r], s);
        }
    #pragma unroll
    for (int off = 1; off < 16; off <<= 1)
        #pragma unroll
        for (int r = 0; r < 4; r++) mx[r] = fmaxf(mx[r], __shfl_xor(mx[r], off, 64));
    float sum[4] = {0.f, 0.f, 0.f, 0.f};
    #pragma unroll
    for (int mt = 0; mt < 12; mt++)
        #pragma unroll
        for (int r = 0; r < 4; r++) {
            float p = __expf(sacc[mt][r] - mx[r]);
            sacc[mt][r] = p;
            sum[r] += p;
        }
    #pragma unroll
    for (int off = 1; off < 16; off <<= 1)
        #pragma unroll
        for (int r = 0; r < 4; r++) sum[r] += __shfl_xor(sum[r], off, 64);
    float inv[4];
    #pragma unroll
    for (int r = 0; r < 4; r++) inv[r] = 1.0f / sum[r];

    #pragma unroll
    for (int mt = 0; mt < 12; mt++)
        #pragma unroll
        for (int r = 0; r < 4; r++)
            Ps[(16 * w + quad * 4 + r) * 200 + 16 * mt + l16] = f2bf(sacc[mt][r] * inv[r]);
    __syncthreads();

    const size_t vbase = ((size_t)(b * HH + h) * DHH) * SS;
    if (kb >= 0) {
        #pragma unroll
        for (int i = 0; i < 6; i++) {
            int chunk = i * 256 + t;
            int d = chunk / 24, c0 = (chunk % 24) * 8;
            bfrag val = *reinterpret_cast<const bfrag*>(v + vbase + (size_t)d * SS + kb + c0);
            *reinterpret_cast<bfrag*>(&Vt[d * 200 + c0]) = val;
        }
    } else {
        for (int i = 0; i < 6; i++) {
            int chunk = i * 256 + t;
            int d = chunk / 24, c0 = (chunk % 24) * 8;
            unsigned short tmp[8];
            for (int j2 = 0; j2 < 8; j2++) {
                int src = kb + c0 + j2; if (src < 0) src = 0;
                tmp[j2] = v[vbase + (size_t)d * SS + src];
            }
            for (int j2 = 0; j2 < 8; j2++) Vt[d * 200 + c0 + j2] = tmp[j2];
        }
    }
    __syncthreads();

    f32x4 zacc[4] = {};
    #pragma unroll
    for (int c0 = 0; c0 < 192; c0 += 32) {
        bfrag a = *reinterpret_cast<const bfrag*>(&Ps[(16 * w + l16) * 200 + c0 + quad * 8]);
        #pragma unroll
        for (int nt = 0; nt < 4; nt++) {
            bfrag bf = *reinterpret_cast<const bfrag*>(&Vt[(16 * nt + l16) * 200 + c0 + quad * 8]);
            zacc[nt] = __builtin_amdgcn_mfma_f32_16x16x32_bf16(a, bf, zacc[nt], 0, 0, 0);
        }
    }
    #pragma unroll
    for (int nt = 0; nt < 4; nt++)
        #pragma unroll
        for (int r = 0; r < 4; r++) {
            int row = 16 * w + quad * 4 + r;
            int d = 16 * nt + l16;
            z[((size_t)(b * SS + qb + row)) * (HH * DHH) + h * DHH + d] = f2bf(zacc[nt][r]);
        }
}

// ---------------- Kernel 3: output projection (both operands DMA-staged) --------
__global__ __launch_bounds__(256) void out_gemm_kernel(
    const unsigned short* __restrict__ Z,
    const unsigned short* __restrict__ Wot,
    const float* __restrict__ bo,
    float* __restrict__ out)
{
    const int mt0 = blockIdx.x * 128;
    const int n0  = blockIdx.y * 128;

    __shared__ unsigned short smem[8192];
    unsigned short* As = smem;
    unsigned short* Bs = smem + 4096;

    const int t = threadIdx.x;
    const int l = t & 63, w4 = t >> 6;
    const int l16 = l & 15, quad = l >> 4;
    const int wr = w4 >> 1, wc = w4 & 1;
    const int swz = (l16 >> 1) & 3;

    f32x4 acc[16] = {};

    for (int k0 = 0; k0 < DD; k0 += 32) {
        #pragma unroll
        for (int j = 0; j < 2; j++) {
            int eoff = (w4 * 2 + j) * 512;
            int e = eoff + l * 8;
            int row = e >> 5, cs = (e & 31) >> 3;
            int k8 = cs ^ ((row >> 1) & 3);
            __builtin_amdgcn_global_load_lds(
                AS1(Z + (size_t)(mt0 + row) * DD + k0 + k8 * 8),
                AS3(As + eoff), 16, 0, 0);
            __builtin_amdgcn_global_load_lds(
                AS1(Wot + (size_t)(n0 + row) * DD + k0 + k8 * 8),
                AS3(Bs + eoff), 16, 0, 0);
        }
        __syncthreads();
        bfrag af[4], bg[4];
        #pragma unroll
        for (int mi = 0; mi < 4; mi++)
            af[mi] = *reinterpret_cast<const bfrag*>(&As[(wr * 64 + mi * 16 + l16) * 32 + ((quad ^ swz) * 8)]);
        #pragma unroll
        for (int ni = 0; ni < 4; ni++)
            bg[ni] = *reinterpret_cast<const bfrag*>(&Bs[(wc * 64 + ni * 16 + l16) * 32 + ((quad ^ swz) * 8)]);
        #pragma unroll
        for (int mi = 0; mi < 4; mi++)
            #pragma unroll
            for (int ni = 0; ni < 4; ni++)
                acc[mi * 4 + ni] = __builtin_amdgcn_mfma_f32_16x16x32_bf16(af[mi], bg[ni], acc[mi * 4 + ni], 0, 0, 0);
        __syncthreads();
    }

    #pragma unroll
    for (int ni = 0; ni < 4; ni++) {
        int n = n0 + wc * 64 + ni * 16 + l16;
        float bv0 = bo[n];
        #pragma unroll
        for (int mi = 0; mi < 4; mi++)
            #pragma unroll
            for (int r = 0; r < 4; r++) {
                int m = mt0 + wr * 64 + mi * 16 + quad * 4 + r;
                out[(size_t)m * DD + n] = acc[mi * 4 + ni][r] + bv0;
            }
    }
}

extern "C" void kernel_launch(void* const* d_in, const int* in_sizes, int n_in,
                              void* d_out, int out_size, void* d_ws, size_t ws_size,
                              hipStream_t stream) {
    const float* Xq = (const float*)d_in[0];
    const float* Xk = (const float*)d_in[1];
    const float* Xv = (const float*)d_in[2];
    const float* Wq = (const float*)d_in[3];
    const float* Wk = (const float*)d_in[4];
    const float* Wv = (const float*)d_in[5];
    const float* Wo = (const float*)d_in[6];
    const float* bq = (const float*)d_in[7];
    const float* bk = (const float*)d_in[8];
    const float* bv = (const float*)d_in[9];
    const float* bo = (const float*)d_in[10];
    float* out = (float*)d_out;

    const size_t seg = (size_t)BB * HH * SS * DHH;   // 3,145,728 bf16 elems
    unsigned short* q   = (unsigned short*)d_ws;
    unsigned short* k   = q + seg;
    unsigned short* v   = k + seg;
    unsigned short* z   = v + seg;
    unsigned short* Wt  = z + seg;                   // 3*768*768
    unsigned short* Wot = Wt + (size_t)3 * DD * DD;  // 768*768
    float2* rope = (float2*)(Wot + (size_t)DD * DD); // 2048*32 float2 (8B-aligned)

    pack_kernel<<<dim3(832), 256, 0, stream>>>(Wq, Wk, Wv, Wo, Wt, Wot, rope);
    qkv_gemm_kernel<<<dim3(MM / 128, DD / 128, 3), 256, 0, stream>>>(
        Xq, Xk, Xv, Wt, bq, bk, bv, rope, q, k, v);
    attn_kernel<<<dim3(SS / 64, HH, BB), 256, 0, stream>>>(q, k, v, z);
    out_gemm_kernel<<<dim3(MM / 128, DD / 128), 256, 0, stream>>>(z, Wot, bo, out);
}

// Round 3
// 169.103 us; speedup vs baseline: 1.3136x; 1.1218x over previous
//
#include <hip/hip_runtime.h>
#include <hip/hip_bf16.h>

#define BB 2
#define SS 2048
#define DD 768
#define HH 12
#define DHH 64
#define WIN 128
#define MM (BB*SS)

typedef __attribute__((ext_vector_type(8))) short bfrag;
typedef __attribute__((ext_vector_type(4))) float f32x4;

#define AS3(p) ((__attribute__((address_space(3))) void*)(p))
#define AS1(p) ((const __attribute__((address_space(1))) void*)(p))

__device__ inline unsigned short f2bf(float f) {
    union { __hip_bfloat16 h; unsigned short u; } cv;
    cv.h = __float2bfloat16(f);
    return cv.u;
}

// Stage a R x 32 bf16 tile (row-major, global stride DD) into LDS via DMA,
// 16B chunks XOR-swizzled: chunk cs at row goes to slot cs ^ ((row>>1)&3).
// Matches ds_read side swz = (l16>>1)&3 (verified conflict-free in round 2).
__device__ inline void stage128(unsigned short* dst, const unsigned short* src,
                                int w4, int l) {
    #pragma unroll
    for (int j = 0; j < 2; j++) {
        int eoff = (w4 * 2 + j) * 512;
        int e = eoff + l * 8;
        int row = e >> 5;
        int k8 = ((e >> 3) & 3) ^ ((row >> 1) & 3);
        __builtin_amdgcn_global_load_lds(AS1(src + (size_t)row * DD + k8 * 8),
                                         AS3(dst + eoff), 16, 0, 0);
    }
}
__device__ inline void stage64(unsigned short* dst, const unsigned short* src,
                               int w4, int l) {
    int eoff = w4 * 512;
    int e = eoff + l * 8;
    int row = e >> 5;
    int k8 = ((e >> 3) & 3) ^ ((row >> 1) & 3);
    __builtin_amdgcn_global_load_lds(AS1(src + (size_t)row * DD + k8 * 8),
                                     AS3(dst + eoff), 16, 0, 0);
}

// ---------------- Kernel 0: pack ----------------
// [0,432): W_{Q,K,V} (H,D,DH) -> Wt[proj][h*64+dh][d]     (B^T bf16)
// [432,576): W_O (H*DH, D)    -> Wot[n][k]                (B^T bf16)
// [576,832): rope table float2(sin,cos)[p][i2]
// [832,3136): X fp32 -> bf16  (3 slabs of 4096x768)
__global__ __launch_bounds__(256) void pack_kernel(
    const float* __restrict__ Xq, const float* __restrict__ Xk, const float* __restrict__ Xv,
    const float* __restrict__ Wq, const float* __restrict__ Wk, const float* __restrict__ Wv,
    const float* __restrict__ Wo,
    unsigned short* __restrict__ Wt, unsigned short* __restrict__ Wot,
    float2* __restrict__ rope, unsigned short* __restrict__ Xbf)
{
    __shared__ float T[64][65];
    const int bid = blockIdx.x, t = threadIdx.x;
    if (bid < 432) {
        int proj = bid / 144, rem = bid % 144;
        int h = rem / 12, d0 = (rem % 12) * 64;
        const float* src = (proj == 0 ? Wq : (proj == 1 ? Wk : Wv)) + (size_t)h * DD * DHH;
        int row = t >> 2, c0 = (t & 3) * 16;
        const float4* p4 = reinterpret_cast<const float4*>(src + (size_t)(d0 + row) * DHH + c0);
        float4 x0 = p4[0], x1 = p4[1], x2 = p4[2], x3 = p4[3];
        float* tr = &T[row][c0];
        tr[0]=x0.x; tr[1]=x0.y; tr[2]=x0.z; tr[3]=x0.w;
        tr[4]=x1.x; tr[5]=x1.y; tr[6]=x1.z; tr[7]=x1.w;
        tr[8]=x2.x; tr[9]=x2.y; tr[10]=x2.z; tr[11]=x2.w;
        tr[12]=x3.x; tr[13]=x3.y; tr[14]=x3.z; tr[15]=x3.w;
        __syncthreads();
        int dh = t >> 2;
        unsigned short tmp[16];
        #pragma unroll
        for (int j = 0; j < 16; j++) tmp[j] = f2bf(T[c0 + j][dh]);
        unsigned short* dst = Wt + (size_t)proj * DD * DD + (size_t)(h * 64 + dh) * DD + d0 + c0;
        *reinterpret_cast<bfrag*>(dst)     = *reinterpret_cast<bfrag*>(tmp);
        *reinterpret_cast<bfrag*>(dst + 8) = *reinterpret_cast<bfrag*>(tmp + 8);
    } else if (bid < 576) {
        int id2 = bid - 432;
        int k0 = (id2 / 12) * 64, n0 = (id2 % 12) * 64;
        int row = t >> 2, c0 = (t & 3) * 16;
        const float4* p4 = reinterpret_cast<const float4*>(Wo + (size_t)(k0 + row) * DD + n0 + c0);
        float4 x0 = p4[0], x1 = p4[1], x2 = p4[2], x3 = p4[3];
        float* tr = &T[row][c0];
        tr[0]=x0.x; tr[1]=x0.y; tr[2]=x0.z; tr[3]=x0.w;
        tr[4]=x1.x; tr[5]=x1.y; tr[6]=x1.z; tr[7]=x1.w;
        tr[8]=x2.x; tr[9]=x2.y; tr[10]=x2.z; tr[11]=x2.w;
        tr[12]=x3.x; tr[13]=x3.y; tr[14]=x3.z; tr[15]=x3.w;
        __syncthreads();
        int nr = t >> 2;
        unsigned short tmp[16];
        #pragma unroll
        for (int j = 0; j < 16; j++) tmp[j] = f2bf(T[c0 + j][nr]);
        unsigned short* dst = Wot + (size_t)(n0 + nr) * DD + k0 + c0;
        *reinterpret_cast<bfrag*>(dst)     = *reinterpret_cast<bfrag*>(tmp);
        *reinterpret_cast<bfrag*>(dst + 8) = *reinterpret_cast<bfrag*>(tmp + 8);
    } else if (bid < 832) {
        int idx = (bid - 576) * 256 + t;   // p in [0,2048), i2 in [0,32)
        int p = idx >> 5, i2 = idx & 31;
        float inv_freq = exp2f(-(float)i2 * (13.287712379549449f / 32.0f));
        float s, c;
        sincosf((float)p * inv_freq, &s, &c);
        rope[idx] = make_float2(s, c);
    } else {
        int i = bid - 832;                  // 2304 blocks x 4096 elems
        int proj = i / 768;
        size_t off = (size_t)(i % 768) * 4096 + t * 16;
        const float* src = (proj == 0 ? Xq : (proj == 1 ? Xk : Xv)) + off;
        const float4* p4 = reinterpret_cast<const float4*>(src);
        float4 a0 = p4[0], a1 = p4[1], a2 = p4[2], a3 = p4[3];
        unsigned short u[16];
        u[0]=f2bf(a0.x); u[1]=f2bf(a0.y); u[2]=f2bf(a0.z); u[3]=f2bf(a0.w);
        u[4]=f2bf(a1.x); u[5]=f2bf(a1.y); u[6]=f2bf(a1.z); u[7]=f2bf(a1.w);
        u[8]=f2bf(a2.x); u[9]=f2bf(a2.y); u[10]=f2bf(a2.z); u[11]=f2bf(a2.w);
        u[12]=f2bf(a3.x); u[13]=f2bf(a3.y); u[14]=f2bf(a3.z); u[15]=f2bf(a3.w);
        unsigned short* dst = Xbf + (size_t)proj * MM * DD + off;
        *reinterpret_cast<bfrag*>(dst)     = *reinterpret_cast<bfrag*>(u);
        *reinterpret_cast<bfrag*>(dst + 8) = *reinterpret_cast<bfrag*>(u + 8);
    }
}

// ---------------- Kernel 1: QKV GEMM (dbuf DMA) + bias + RoPE ----------------
// grid (32, 6, 3): 128x128 tile, BK=32, double-buffered global_load_lds.
__global__ __launch_bounds__(256) void qkv_gemm_kernel(
    const unsigned short* __restrict__ Xbf,
    const unsigned short* __restrict__ Wt,
    const float* __restrict__ bq, const float* __restrict__ bk, const float* __restrict__ bv,
    const float2* __restrict__ rope,
    unsigned short* __restrict__ qo, unsigned short* __restrict__ ko, unsigned short* __restrict__ vo)
{
    const int mt0  = blockIdx.x * 128;
    const int n0   = blockIdx.y * 128;
    const int proj = blockIdx.z;
    const unsigned short* X = Xbf + (size_t)proj * MM * DD + (size_t)mt0 * DD;
    const unsigned short* W = Wt + (size_t)proj * DD * DD + (size_t)n0 * DD;
    const float* bias = proj == 0 ? bq : (proj == 1 ? bk : bv);

    // staging: As0[0,4096) Bs0[4096,8192) As1[8192,12288) Bs1[12288,16384)
    // epilogue Ct (128 x stride140) aliases everything
    __shared__ unsigned short smem[128 * 140];

    const int t = threadIdx.x;
    const int l = t & 63, w4 = t >> 6;
    const int l16 = l & 15, quad = l >> 4;
    const int wr = w4 >> 1, wc = w4 & 1;
    const int swz = (l16 >> 1) & 3;

    f32x4 acc[16] = {};

    stage128(smem,        X, w4, l);
    stage128(smem + 4096, W, w4, l);

    for (int it = 0; it < 24; ++it) {
        unsigned short* Ac = smem + (it & 1) * 8192;
        unsigned short* Bc = Ac + 4096;
        __syncthreads();   // staged tile `it` resident; prev reads of other buf done
        if (it < 23) {
            unsigned short* An = smem + ((it + 1) & 1) * 8192;
            stage128(An,        X + (it + 1) * 32, w4, l);
            stage128(An + 4096, W + (it + 1) * 32, w4, l);
        }
        bfrag af[4], bg[4];
        #pragma unroll
        for (int mi = 0; mi < 4; mi++)
            af[mi] = *reinterpret_cast<const bfrag*>(&Ac[(wr * 64 + mi * 16 + l16) * 32 + ((quad ^ swz) * 8)]);
        #pragma unroll
        for (int ni = 0; ni < 4; ni++)
            bg[ni] = *reinterpret_cast<const bfrag*>(&Bc[(wc * 64 + ni * 16 + l16) * 32 + ((quad ^ swz) * 8)]);
        #pragma unroll
        for (int mi = 0; mi < 4; mi++)
            #pragma unroll
            for (int ni = 0; ni < 4; ni++)
                acc[mi * 4 + ni] = __builtin_amdgcn_mfma_f32_16x16x32_bf16(af[mi], bg[ni], acc[mi * 4 + ni], 0, 0, 0);
    }
    __syncthreads();

    unsigned short* Ct = smem;   // stride 140
    const int b = mt0 >> 11;
    if (proj < 2) {
        #pragma unroll
        for (int ni = 0; ni < 4; ni++) {
            int nloc = wc * 64 + ni * 16 + l16;
            int n = n0 + nloc;
            int dh = n & 63;
            float bv0 = bias[n];
            float bv1 = bias[n ^ 32];
            float sgn = (dh & 32) ? 1.0f : -1.0f;
            const float2* rp = rope + (dh & 31);
            #pragma unroll
            for (int mi = 0; mi < 4; mi++)
                #pragma unroll
                for (int r = 0; r < 4; r++) {
                    int ploc = wr * 64 + mi * 16 + quad * 4 + r;
                    int p = (mt0 + ploc) & (SS - 1);
                    float2 sc = rp[p << 5];
                    float val = acc[mi * 4 + ni][r] + bv0;
                    float pr  = acc[mi * 4 + (ni ^ 2)][r] + bv1;
                    Ct[ploc * 140 + nloc] = f2bf(val * sc.y + sgn * pr * sc.x);
                }
        }
        __syncthreads();
        unsigned short* dst = (proj == 0) ? qo : ko;
        #pragma unroll
        for (int jj = 0; jj < 8; jj++) {
            int id = jj * 256 + t;
            int row = id >> 4, c = (id & 15) * 8;
            int n = n0 + c, h = n >> 6, dh = n & 63;
            int p = (mt0 + row) & (SS - 1);
            bfrag vv = *reinterpret_cast<const bfrag*>(&Ct[row * 140 + c]);
            *reinterpret_cast<bfrag*>(dst + (((size_t)(b * HH + h) * SS + p) << 6) + dh) = vv;
        }
    } else {
        #pragma unroll
        for (int ni = 0; ni < 4; ni++) {
            int nloc = wc * 64 + ni * 16 + l16;
            float bv0 = bias[n0 + nloc];
            #pragma unroll
            for (int mi = 0; mi < 4; mi++)
                #pragma unroll
                for (int r = 0; r < 4; r++) {
                    int ploc = wr * 64 + mi * 16 + quad * 4 + r;
                    Ct[nloc * 140 + ploc] = f2bf(acc[mi * 4 + ni][r] + bv0);
                }
        }
        __syncthreads();
        int p0 = mt0 & (SS - 1);
        #pragma unroll
        for (int jj = 0; jj < 8; jj++) {
            int id = jj * 256 + t;
            int row = id >> 4, c = (id & 15) * 8;
            int n = n0 + row, h = n >> 6, dh = n & 63;
            bfrag vv = *reinterpret_cast<const bfrag*>(&Ct[row * 140 + c]);
            *reinterpret_cast<bfrag*>(vo + (((size_t)(b * HH + h) * DHH + dh) << 11) + p0 + c) = vv;
        }
    }
}

// ---------------- Kernel 2: sliding-window attention (unchanged) ----------------
__global__ __launch_bounds__(256) void attn_kernel(
    const unsigned short* __restrict__ q,
    const unsigned short* __restrict__ k,
    const unsigned short* __restrict__ v,
    unsigned short* __restrict__ z)
{
    const int qb = blockIdx.x * 64;
    const int h  = blockIdx.y;
    const int b  = blockIdx.z;
    const int kb = qb - WIN;

    __shared__ unsigned short QK[64 * 72 + 192 * 72];
    __shared__ unsigned short Ps[64 * 200];
    unsigned short* Qs = QK;
    unsigned short* Ks = QK + 64 * 72;
    unsigned short* Vt = QK;

    const int t = threadIdx.x;
    const int w = t >> 6, lane = t & 63;
    const int l16 = lane & 15, quad = lane >> 4;

    const size_t qkbase = ((size_t)(b * HH + h) * SS) * DHH;
    #pragma unroll
    for (int i = 0; i < 2; i++) {
        int chunk = i * 256 + t;
        int row = chunk >> 3, c0 = (chunk & 7) * 8;
        bfrag val = *reinterpret_cast<const bfrag*>(q + qkbase + (size_t)(qb + row) * DHH + c0);
        *reinterpret_cast<bfrag*>(&Qs[row * 72 + c0]) = val;
    }
    #pragma unroll
    for (int i = 0; i < 6; i++) {
        int chunk = i * 256 + t;
        int row = chunk >> 3, c0 = (chunk & 7) * 8;
        int src = kb + row; if (src < 0) src = 0;
        bfrag val = *reinterpret_cast<const bfrag*>(k + qkbase + (size_t)src * DHH + c0);
        *reinterpret_cast<bfrag*>(&Ks[row * 72 + c0]) = val;
    }
    __syncthreads();

    f32x4 sacc[12] = {};
    #pragma unroll
    for (int kk = 0; kk < 64; kk += 32) {
        bfrag a = *reinterpret_cast<const bfrag*>(&Qs[(16 * w + l16) * 72 + kk + quad * 8]);
        #pragma unroll
        for (int mt = 0; mt < 12; mt++) {
            bfrag bf = *reinterpret_cast<const bfrag*>(&Ks[(16 * mt + l16) * 72 + kk + quad * 8]);
            sacc[mt] = __builtin_amdgcn_mfma_f32_16x16x32_bf16(a, bf, sacc[mt], 0, 0, 0);
        }
    }

    float mx[4] = {-3e38f, -3e38f, -3e38f, -3e38f};
    #pragma unroll
    for (int mt = 0; mt < 12; mt++)
        #pragma unroll
        for (int r = 0; r < 4; r++) {
            int row = 16 * w + quad * 4 + r;
            int c = 16 * mt + l16;
            bool valid = (c > row) && (c <= row + WIN) && (kb + c >= 0);
            float s = valid ? sacc[mt][r] * 0.125f : -3e38f;
            sacc[mt][r] = s;
            mx[r] = fmaxf(mx[r], s);
        }
    #pragma unroll
    for (int off = 1; off < 16; off <<= 1)
        #pragma unroll
        for (int r = 0; r < 4; r++) mx[r] = fmaxf(mx[r], __shfl_xor(mx[r], off, 64));
    float sum[4] = {0.f, 0.f, 0.f, 0.f};
    #pragma unroll
    for (int mt = 0; mt < 12; mt++)
        #pragma unroll
        for (int r = 0; r < 4; r++) {
            float p = __expf(sacc[mt][r] - mx[r]);
            sacc[mt][r] = p;
            sum[r] += p;
        }
    #pragma unroll
    for (int off = 1; off < 16; off <<= 1)
        #pragma unroll
        for (int r = 0; r < 4; r++) sum[r] += __shfl_xor(sum[r], off, 64);
    float inv[4];
    #pragma unroll
    for (int r = 0; r < 4; r++) inv[r] = 1.0f / sum[r];

    #pragma unroll
    for (int mt = 0; mt < 12; mt++)
        #pragma unroll
        for (int r = 0; r < 4; r++)
            Ps[(16 * w + quad * 4 + r) * 200 + 16 * mt + l16] = f2bf(sacc[mt][r] * inv[r]);
    __syncthreads();

    const size_t vbase = ((size_t)(b * HH + h) * DHH) * SS;
    if (kb >= 0) {
        #pragma unroll
        for (int i = 0; i < 6; i++) {
            int chunk = i * 256 + t;
            int d = chunk / 24, c0 = (chunk % 24) * 8;
            bfrag val = *reinterpret_cast<const bfrag*>(v + vbase + (size_t)d * SS + kb + c0);
            *reinterpret_cast<bfrag*>(&Vt[d * 200 + c0]) = val;
        }
    } else {
        for (int i = 0; i < 6; i++) {
            int chunk = i * 256 + t;
            int d = chunk / 24, c0 = (chunk % 24) * 8;
            unsigned short tmp[8];
            for (int j2 = 0; j2 < 8; j2++) {
                int src = kb + c0 + j2; if (src < 0) src = 0;
                tmp[j2] = v[vbase + (size_t)d * SS + src];
            }
            for (int j2 = 0; j2 < 8; j2++) Vt[d * 200 + c0 + j2] = tmp[j2];
        }
    }
    __syncthreads();

    f32x4 zacc[4] = {};
    #pragma unroll
    for (int c0 = 0; c0 < 192; c0 += 32) {
        bfrag a = *reinterpret_cast<const bfrag*>(&Ps[(16 * w + l16) * 200 + c0 + quad * 8]);
        #pragma unroll
        for (int nt = 0; nt < 4; nt++) {
            bfrag bf = *reinterpret_cast<const bfrag*>(&Vt[(16 * nt + l16) * 200 + c0 + quad * 8]);
            zacc[nt] = __builtin_amdgcn_mfma_f32_16x16x32_bf16(a, bf, zacc[nt], 0, 0, 0);
        }
    }
    #pragma unroll
    for (int nt = 0; nt < 4; nt++)
        #pragma unroll
        for (int r = 0; r < 4; r++) {
            int row = 16 * w + quad * 4 + r;
            int d = 16 * nt + l16;
            z[((size_t)(b * SS + qb + row)) * (HH * DHH) + h * DHH + d] = f2bf(zacc[nt][r]);
        }
}

// ---------------- Kernel 3: output projection, 64x128 tile, dbuf DMA ----------
__global__ __launch_bounds__(256) void out_gemm_kernel(
    const unsigned short* __restrict__ Z,
    const unsigned short* __restrict__ Wot,
    const float* __restrict__ bo,
    float* __restrict__ out)
{
    const int mt0 = blockIdx.x * 64;
    const int n0  = blockIdx.y * 128;
    const unsigned short* A = Z + (size_t)mt0 * DD;
    const unsigned short* Bw = Wot + (size_t)n0 * DD;

    // As0[0,2048) Bs0[2048,6144) As1[6144,8192) Bs1[8192,12288)
    __shared__ unsigned short smem[12288];

    const int t = threadIdx.x;
    const int l = t & 63, w4 = t >> 6;
    const int l16 = l & 15, quad = l >> 4;
    const int swz = (l16 >> 1) & 3;

    f32x4 acc[8] = {};

    stage64 (smem,        A,  w4, l);
    stage128(smem + 2048, Bw, w4, l);

    for (int it = 0; it < 24; ++it) {
        unsigned short* Ac = smem + (it & 1) * 6144;
        unsigned short* Bc = Ac + 2048;
        __syncthreads();
        if (it < 23) {
            unsigned short* An = smem + ((it + 1) & 1) * 6144;
            stage64 (An,        A  + (it + 1) * 32, w4, l);
            stage128(An + 2048, Bw + (it + 1) * 32, w4, l);
        }
        bfrag af[4], bg[2];
        #pragma unroll
        for (int mi = 0; mi < 4; mi++)
            af[mi] = *reinterpret_cast<const bfrag*>(&Ac[(mi * 16 + l16) * 32 + ((quad ^ swz) * 8)]);
        #pragma unroll
        for (int ni = 0; ni < 2; ni++)
            bg[ni] = *reinterpret_cast<const bfrag*>(&Bc[(w4 * 32 + ni * 16 + l16) * 32 + ((quad ^ swz) * 8)]);
        #pragma unroll
        for (int mi = 0; mi < 4; mi++)
            #pragma unroll
            for (int ni = 0; ni < 2; ni++)
                acc[mi * 2 + ni] = __builtin_amdgcn_mfma_f32_16x16x32_bf16(af[mi], bg[ni], acc[mi * 2 + ni], 0, 0, 0);
    }

    #pragma unroll
    for (int ni = 0; ni < 2; ni++) {
        int n = n0 + w4 * 32 + ni * 16 + l16;
        float bv0 = bo[n];
        #pragma unroll
        for (int mi = 0; mi < 4; mi++)
            #pragma unroll
            for (int r = 0; r < 4; r++) {
                int m = mt0 + mi * 16 + quad * 4 + r;
                out[(size_t)m * DD + n] = acc[mi * 2 + ni][r] + bv0;
            }
    }
}

extern "C" void kernel_launch(void* const* d_in, const int* in_sizes, int n_in,
                              void* d_out, int out_size, void* d_ws, size_t ws_size,
                              hipStream_t stream) {
    const float* Xq = (const float*)d_in[0];
    const float* Xk = (const float*)d_in[1];
    const float* Xv = (const float*)d_in[2];
    const float* Wq = (const float*)d_in[3];
    const float* Wk = (const float*)d_in[4];
    const float* Wv = (const float*)d_in[5];
    const float* Wo = (const float*)d_in[6];
    const float* bq = (const float*)d_in[7];
    const float* bk = (const float*)d_in[8];
    const float* bv = (const float*)d_in[9];
    const float* bo = (const float*)d_in[10];
    float* out = (float*)d_out;

    const size_t seg = (size_t)BB * HH * SS * DHH;   // 3,145,728 bf16 elems
    unsigned short* q   = (unsigned short*)d_ws;
    unsigned short* k   = q + seg;
    unsigned short* v   = k + seg;
    unsigned short* z   = v + seg;
    unsigned short* Wt  = z + seg;                    // 3*768*768
    unsigned short* Wot = Wt + (size_t)3 * DD * DD;   // 768*768
    float2* rope = (float2*)(Wot + (size_t)DD * DD);  // 2048*32 float2
    unsigned short* Xbf = (unsigned short*)(rope + 2048 * 32); // 3*4096*768

    pack_kernel<<<dim3(3136), 256, 0, stream>>>(Xq, Xk, Xv, Wq, Wk, Wv, Wo, Wt, Wot, rope, Xbf);
    qkv_gemm_kernel<<<dim3(MM / 128, DD / 128, 3), 256, 0, stream>>>(
        Xbf, Wt, bq, bk, bv, rope, q, k, v);
    attn_kernel<<<dim3(SS / 64, HH, BB), 256, 0, stream>>>(q, k, v, z);
    out_gemm_kernel<<<dim3(MM / 64, DD / 128), 256, 0, stream>>>(z, Wot, bo, out);
}

// Round 4
// 168.991 us; speedup vs baseline: 1.3144x; 1.0007x over previous
//
#include <hip/hip_runtime.h>
#include <hip/hip_bf16.h>

#define BB 2
#define SS 2048
#define DD 768
#define HH 12
#define DHH 64
#define WIN 128
#define MM (BB*SS)

typedef __attribute__((ext_vector_type(8))) short bfrag;
typedef __attribute__((ext_vector_type(4))) float f32x4;
typedef __attribute__((ext_vector_type(4))) short s16x4;

#define AS3(p) ((__attribute__((address_space(3))) void*)(p))
#define AS1(p) ((const __attribute__((address_space(1))) void*)(p))

__device__ inline unsigned short f2bf(float f) {
    union { __hip_bfloat16 h; unsigned short u; } cv;
    cv.h = __float2bfloat16(f);
    return cv.u;
}

// ---------------- Kernel 0: pack ----------------
// [0,432): W_{Q,K,V} (H,D,DH) -> Wt[proj][h*64+dh][d]     (B^T bf16)
// [432,576): W_O (H*DH, D)    -> Wot[n][k]                (B^T bf16)
// [576,832): rope table float2(sin,cos)[p][i2]
// [832,3136): X fp32 -> bf16  (3 slabs of 4096x768)
__global__ __launch_bounds__(256) void pack_kernel(
    const float* __restrict__ Xq, const float* __restrict__ Xk, const float* __restrict__ Xv,
    const float* __restrict__ Wq, const float* __restrict__ Wk, const float* __restrict__ Wv,
    const float* __restrict__ Wo,
    unsigned short* __restrict__ Wt, unsigned short* __restrict__ Wot,
    float2* __restrict__ rope, unsigned short* __restrict__ Xbf)
{
    __shared__ float T[64][65];
    const int bid = blockIdx.x, t = threadIdx.x;
    if (bid < 432) {
        int proj = bid / 144, rem = bid % 144;
        int h = rem / 12, d0 = (rem % 12) * 64;
        const float* src = (proj == 0 ? Wq : (proj == 1 ? Wk : Wv)) + (size_t)h * DD * DHH;
        int row = t >> 2, c0 = (t & 3) * 16;
        const float4* p4 = reinterpret_cast<const float4*>(src + (size_t)(d0 + row) * DHH + c0);
        float4 x0 = p4[0], x1 = p4[1], x2 = p4[2], x3 = p4[3];
        float* tr = &T[row][c0];
        tr[0]=x0.x; tr[1]=x0.y; tr[2]=x0.z; tr[3]=x0.w;
        tr[4]=x1.x; tr[5]=x1.y; tr[6]=x1.z; tr[7]=x1.w;
        tr[8]=x2.x; tr[9]=x2.y; tr[10]=x2.z; tr[11]=x2.w;
        tr[12]=x3.x; tr[13]=x3.y; tr[14]=x3.z; tr[15]=x3.w;
        __syncthreads();
        int dh = t >> 2;
        unsigned short tmp[16];
        #pragma unroll
        for (int j = 0; j < 16; j++) tmp[j] = f2bf(T[c0 + j][dh]);
        unsigned short* dst = Wt + (size_t)proj * DD * DD + (size_t)(h * 64 + dh) * DD + d0 + c0;
        *reinterpret_cast<bfrag*>(dst)     = *reinterpret_cast<bfrag*>(tmp);
        *reinterpret_cast<bfrag*>(dst + 8) = *reinterpret_cast<bfrag*>(tmp + 8);
    } else if (bid < 576) {
        int id2 = bid - 432;
        int k0 = (id2 / 12) * 64, n0 = (id2 % 12) * 64;
        int row = t >> 2, c0 = (t & 3) * 16;
        const float4* p4 = reinterpret_cast<const float4*>(Wo + (size_t)(k0 + row) * DD + n0 + c0);
        float4 x0 = p4[0], x1 = p4[1], x2 = p4[2], x3 = p4[3];
        float* tr = &T[row][c0];
        tr[0]=x0.x; tr[1]=x0.y; tr[2]=x0.z; tr[3]=x0.w;
        tr[4]=x1.x; tr[5]=x1.y; tr[6]=x1.z; tr[7]=x1.w;
        tr[8]=x2.x; tr[9]=x2.y; tr[10]=x2.z; tr[11]=x2.w;
        tr[12]=x3.x; tr[13]=x3.y; tr[14]=x3.z; tr[15]=x3.w;
        __syncthreads();
        int nr = t >> 2;
        unsigned short tmp[16];
        #pragma unroll
        for (int j = 0; j < 16; j++) tmp[j] = f2bf(T[c0 + j][nr]);
        unsigned short* dst = Wot + (size_t)(n0 + nr) * DD + k0 + c0;
        *reinterpret_cast<bfrag*>(dst)     = *reinterpret_cast<bfrag*>(tmp);
        *reinterpret_cast<bfrag*>(dst + 8) = *reinterpret_cast<bfrag*>(tmp + 8);
    } else if (bid < 832) {
        int idx = (bid - 576) * 256 + t;   // p in [0,2048), i2 in [0,32)
        int p = idx >> 5, i2 = idx & 31;
        float inv_freq = exp2f(-(float)i2 * (13.287712379549449f / 32.0f));
        float s, c;
        sincosf((float)p * inv_freq, &s, &c);
        rope[idx] = make_float2(s, c);
    } else {
        int i = bid - 832;                  // 2304 blocks x 4096 elems
        int proj = i / 768;
        size_t off = (size_t)(i % 768) * 4096 + t * 16;
        const float* src = (proj == 0 ? Xq : (proj == 1 ? Xk : Xv)) + off;
        const float4* p4 = reinterpret_cast<const float4*>(src);
        float4 a0 = p4[0], a1 = p4[1], a2 = p4[2], a3 = p4[3];
        unsigned short u[16];
        u[0]=f2bf(a0.x); u[1]=f2bf(a0.y); u[2]=f2bf(a0.z); u[3]=f2bf(a0.w);
        u[4]=f2bf(a1.x); u[5]=f2bf(a1.y); u[6]=f2bf(a1.z); u[7]=f2bf(a1.w);
        u[8]=f2bf(a2.x); u[9]=f2bf(a2.y); u[10]=f2bf(a2.z); u[11]=f2bf(a2.w);
        u[12]=f2bf(a3.x); u[13]=f2bf(a3.y); u[14]=f2bf(a3.z); u[15]=f2bf(a3.w);
        unsigned short* dst = Xbf + (size_t)proj * MM * DD + off;
        *reinterpret_cast<bfrag*>(dst)     = *reinterpret_cast<bfrag*>(u);
        *reinterpret_cast<bfrag*>(dst + 8) = *reinterpret_cast<bfrag*>(u + 8);
    }
}

// ---------------- Kernel 1: QKV GEMM 64x128 tiles (dbuf DMA) + bias + RoPE ------
// grid (64, 6, 3) = 1152 blocks; 24KB LDS + ~80 VGPR -> whole grid co-resident.
__global__ __launch_bounds__(256) void qkv_gemm_kernel(
    const unsigned short* __restrict__ Xbf,
    const unsigned short* __restrict__ Wt,
    const float* __restrict__ bq, const float* __restrict__ bk, const float* __restrict__ bv,
    const float2* __restrict__ rope,
    unsigned short* __restrict__ qo, unsigned short* __restrict__ ko, unsigned short* __restrict__ vo)
{
    const int mt0  = blockIdx.x * 64;
    const int n0   = blockIdx.y * 128;
    const int proj = blockIdx.z;
    const unsigned short* X = Xbf + (size_t)proj * MM * DD + (size_t)mt0 * DD;
    const unsigned short* W = Wt + (size_t)proj * DD * DD + (size_t)n0 * DD;
    const float* bias = proj == 0 ? bq : (proj == 1 ? bk : bv);

    // buf0 [0,6144): A[0,2048) B[2048,6144); buf1 [6144,12288). Ct aliases all.
    __shared__ unsigned short smem[12288];

    const int t = threadIdx.x;
    const int l = t & 63, w4 = t >> 6;
    const int l16 = l & 15, quad = l >> 4;
    const int wr = w4 >> 1, wc = w4 & 1;
    const int swz = (l16 >> 1) & 3;

    f32x4 acc[8] = {};

    // stage one 64x32 A panel + 128x32 B panel = 12 DMA groups, 3 per wave
    #define STAGE_QKV(bufp, k0)                                                   \
        _Pragma("unroll")                                                         \
        for (int j = 0; j < 3; j++) {                                             \
            int g = w4 * 3 + j;                                                   \
            if (g < 4) {                                                          \
                int e = g * 512 + l * 8;                                          \
                int row = e >> 5;                                                 \
                int k8 = ((e >> 3) & 3) ^ ((row >> 1) & 3);                       \
                __builtin_amdgcn_global_load_lds(                                 \
                    AS1(X + (size_t)row * DD + (k0) + k8 * 8),                    \
                    AS3((bufp) + g * 512), 16, 0, 0);                             \
            } else {                                                              \
                int g2 = g - 4;                                                   \
                int e = g2 * 512 + l * 8;                                         \
                int row = e >> 5;                                                 \
                int k8 = ((e >> 3) & 3) ^ ((row >> 1) & 3);                       \
                __builtin_amdgcn_global_load_lds(                                 \
                    AS1(W + (size_t)row * DD + (k0) + k8 * 8),                    \
                    AS3((bufp) + 2048 + g2 * 512), 16, 0, 0);                     \
            }                                                                     \
        }

    STAGE_QKV(smem, 0)

    for (int it = 0; it < 24; ++it) {
        unsigned short* cur = smem + (it & 1) * 6144;
        __syncthreads();
        if (it < 23) {
            unsigned short* nxt = smem + ((it + 1) & 1) * 6144;
            STAGE_QKV(nxt, (it + 1) * 32)
        }
        bfrag af[2], bg[4];
        #pragma unroll
        for (int mi = 0; mi < 2; mi++)
            af[mi] = *reinterpret_cast<const bfrag*>(&cur[(wr * 32 + mi * 16 + l16) * 32 + ((quad ^ swz) * 8)]);
        #pragma unroll
        for (int ni = 0; ni < 4; ni++)
            bg[ni] = *reinterpret_cast<const bfrag*>(&cur[2048 + (wc * 64 + ni * 16 + l16) * 32 + ((quad ^ swz) * 8)]);
        #pragma unroll
        for (int mi = 0; mi < 2; mi++)
            #pragma unroll
            for (int ni = 0; ni < 4; ni++)
                acc[mi * 4 + ni] = __builtin_amdgcn_mfma_f32_16x16x32_bf16(af[mi], bg[ni], acc[mi * 4 + ni], 0, 0, 0);
    }
    __syncthreads();

    unsigned short* Ct = smem;
    const int b = mt0 >> 11;
    const int p0 = mt0 & (SS - 1);
    if (proj < 2) {
        // bias + RoPE in registers (pair dh^32 = microtile ni^2, same lane)
        #pragma unroll
        for (int ni = 0; ni < 4; ni++) {
            int nloc = wc * 64 + ni * 16 + l16;
            int n = n0 + nloc;
            int dh = n & 63;
            float bv0 = bias[n];
            float bv1 = bias[n ^ 32];
            float sgn = (dh & 32) ? 1.0f : -1.0f;
            const float2* rp = rope + (dh & 31);
            #pragma unroll
            for (int mi = 0; mi < 2; mi++)
                #pragma unroll
                for (int r = 0; r < 4; r++) {
                    int ploc = wr * 32 + mi * 16 + quad * 4 + r;
                    float2 sc = rp[(p0 + ploc) << 5];
                    float val = acc[mi * 4 + ni][r] + bv0;
                    float pr  = acc[mi * 4 + (ni ^ 2)][r] + bv1;
                    Ct[ploc * 140 + nloc] = f2bf(val * sc.y + sgn * pr * sc.x);
                }
        }
        __syncthreads();
        unsigned short* dst = (proj == 0) ? qo : ko;
        #pragma unroll
        for (int jj = 0; jj < 4; jj++) {
            int id = jj * 256 + t;
            int row = id >> 4, c = (id & 15) * 8;
            int n = n0 + c, h = n >> 6, dh = n & 63;
            bfrag vv = *reinterpret_cast<const bfrag*>(&Ct[row * 140 + c]);
            *reinterpret_cast<bfrag*>(dst + (((size_t)(b * HH + h) * SS + p0 + row) << 6) + dh) = vv;
        }
    } else {
        // bias only; store transposed (B,H,DH,S); Ct used as [nloc][ploc] stride 72
        #pragma unroll
        for (int ni = 0; ni < 4; ni++) {
            int nloc = wc * 64 + ni * 16 + l16;
            float bv0 = bias[n0 + nloc];
            #pragma unroll
            for (int mi = 0; mi < 2; mi++)
                #pragma unroll
                for (int r = 0; r < 4; r++) {
                    int ploc = wr * 32 + mi * 16 + quad * 4 + r;
                    Ct[nloc * 72 + ploc] = f2bf(acc[mi * 4 + ni][r] + bv0);
                }
        }
        __syncthreads();
        #pragma unroll
        for (int jj = 0; jj < 4; jj++) {
            int id = jj * 256 + t;
            int row = id >> 3, c = (id & 7) * 8;   // row = n-local, c = position chunk
            int n = n0 + row, h = n >> 6, dh = n & 63;
            bfrag vv = *reinterpret_cast<const bfrag*>(&Ct[row * 72 + c]);
            *reinterpret_cast<bfrag*>(vo + (((size_t)(b * HH + h) * DHH + dh) << 11) + p0 + c) = vv;
        }
    }
    #undef STAGE_QKV
}

// ---------------- Kernel 2: sliding-window attention, restructured ----------------
// grid (S/64, H, B) = 768 blocks. K: LDS via DMA (swizzled panels). Q and V^T:
// fragments loaded DIRECTLY from global (contiguous 16B per lane). PV computed as
// Z^T = V^T · P^T. LDS 25.6KB, 2 barriers, V latency hidden under QK+softmax.
__global__ __launch_bounds__(256) void attn_kernel(
    const unsigned short* __restrict__ q,
    const unsigned short* __restrict__ k,
    const unsigned short* __restrict__ v,
    unsigned short* __restrict__ z)
{
    const int qb = blockIdx.x * 64;
    const int h  = blockIdx.y;
    const int b  = blockIdx.z;
    const int kb = qb - WIN;   // may be negative: reads land in prior ws slab (valid, masked)

    __shared__ unsigned short sA[12800];   // K panels [0,12288); Ps aliases [0,12800)

    const int t = threadIdx.x;
    const int w4 = t >> 6, l = t & 63;
    const int l16 = l & 15, quad = l >> 4;
    const int swz = (l16 >> 1) & 3;

    const size_t qkbase = (size_t)(b * HH + h) * SS * DHH;
    const unsigned short* kp = (k + qkbase) + (ptrdiff_t)kb * DHH;
    const unsigned short* vp = (v + (size_t)(b * HH + h) * DHH * SS) + (ptrdiff_t)kb;

    // --- stage K: 6 panels (64rows x 32cols), 24 DMA groups, 6 per wave ---
    #pragma unroll
    for (int j = 0; j < 6; j++) {
        int g = w4 * 6 + j;
        int panel = g >> 2, sub = g & 3;
        int rg = panel >> 1, kpart = panel & 1;
        int e = sub * 512 + l * 8;
        int row = e >> 5;
        int k8 = ((e >> 3) & 3) ^ ((row >> 1) & 3);
        __builtin_amdgcn_global_load_lds(
            AS1(kp + (size_t)(rg * 64 + row) * DHH + kpart * 32 + k8 * 8),
            AS3(sA + panel * 2048 + sub * 512), 16, 0, 0);
    }
    // --- Q fragments direct from global (A-layout: contiguous 8 bf16/lane) ---
    bfrag qf[2];
    #pragma unroll
    for (int kk = 0; kk < 2; kk++)
        qf[kk] = *reinterpret_cast<const bfrag*>(
            q + qkbase + (size_t)(qb + 16 * w4 + l16) * DHH + kk * 32 + quad * 8);
    // --- V^T fragment batch A (c0 = 0,32,64) direct from global ---
    bfrag vfA[12];
    #pragma unroll
    for (int ci = 0; ci < 3; ci++)
        #pragma unroll
        for (int mt = 0; mt < 4; mt++)
            vfA[ci * 4 + mt] = *reinterpret_cast<const bfrag*>(
                vp + (size_t)(16 * mt + l16) * SS + ci * 32 + quad * 8);

    __syncthreads();   // K panels resident

    // --- QK^T: S[q=16*w4+quad*4+r .. ][key=16*mt+l16] ---
    f32x4 sacc[12] = {};
    #pragma unroll
    for (int kk = 0; kk < 2; kk++)
        #pragma unroll
        for (int mt = 0; mt < 12; mt++) {
            int kr = 16 * mt + l16;
            bfrag bf = *reinterpret_cast<const bfrag*>(
                &sA[(((kr >> 6) * 2 + kk) * 2048) + (kr & 63) * 32 + ((quad ^ swz) * 8)]);
            sacc[mt] = __builtin_amdgcn_mfma_f32_16x16x32_bf16(qf[kk], bf, sacc[mt], 0, 0, 0);
        }

    // --- V^T fragment batch B (c0 = 96,128,160): latency hidden under softmax ---
    bfrag vfB[12];
    #pragma unroll
    for (int ci = 0; ci < 3; ci++)
        #pragma unroll
        for (int mt = 0; mt < 4; mt++)
            vfB[ci * 4 + mt] = *reinterpret_cast<const bfrag*>(
                vp + (size_t)(16 * mt + l16) * SS + (ci + 3) * 32 + quad * 8);

    // --- mask + scale + exact softmax (rows 16*w4+quad*4+r, cols 16*mt+l16) ---
    float mx[4] = {-3e38f, -3e38f, -3e38f, -3e38f};
    #pragma unroll
    for (int mt = 0; mt < 12; mt++)
        #pragma unroll
        for (int r = 0; r < 4; r++) {
            int row = 16 * w4 + quad * 4 + r;
            int c = 16 * mt + l16;
            bool valid = (c > row) && (c <= row + WIN) && (kb + c >= 0);
            float s = valid ? sacc[mt][r] * 0.125f : -3e38f;
            sacc[mt][r] = s;
            mx[r] = fmaxf(mx[r], s);
        }
    #pragma unroll
    for (int off = 1; off < 16; off <<= 1)
        #pragma unroll
        for (int r = 0; r < 4; r++) mx[r] = fmaxf(mx[r], __shfl_xor(mx[r], off, 64));
    float sum[4] = {0.f, 0.f, 0.f, 0.f};
    #pragma unroll
    for (int mt = 0; mt < 12; mt++)
        #pragma unroll
        for (int r = 0; r < 4; r++) {
            float p = __expf(sacc[mt][r] - mx[r]);
            sacc[mt][r] = p;
            sum[r] += p;
        }
    #pragma unroll
    for (int off = 1; off < 16; off <<= 1)
        #pragma unroll
        for (int r = 0; r < 4; r++) sum[r] += __shfl_xor(sum[r], off, 64);
    float inv[4];
    #pragma unroll
    for (int r = 0; r < 4; r++) inv[r] = 1.0f / sum[r];

    __syncthreads();   // all K-panel reads complete before Ps overwrites them

    // --- P -> LDS (row-major stride 200). Each wave writes ONLY its own 16-row
    //     strip and reads ONLY its own strip below: no barrier needed after. ---
    unsigned short* Ps = sA;
    #pragma unroll
    for (int mt = 0; mt < 12; mt++)
        #pragma unroll
        for (int r = 0; r < 4; r++)
            Ps[(16 * w4 + quad * 4 + r) * 200 + 16 * mt + l16] = f2bf(sacc[mt][r] * inv[r]);

    // --- PV as Z^T = V^T(A) · P^T(B): D[m=d][n=q-strip] ---
    f32x4 zacc[4] = {};
    #pragma unroll
    for (int ci = 0; ci < 6; ci++) {
        bfrag pb = *reinterpret_cast<const bfrag*>(
            &Ps[(16 * w4 + l16) * 200 + ci * 32 + quad * 8]);
        #pragma unroll
        for (int mt = 0; mt < 4; mt++) {
            bfrag va = (ci < 3) ? vfA[ci * 4 + mt] : vfB[(ci - 3) * 4 + mt];
            zacc[mt] = __builtin_amdgcn_mfma_f32_16x16x32_bf16(va, pb, zacc[mt], 0, 0, 0);
        }
    }
    // lane holds Zt[d=16*mt+quad*4+r][q=16*w4+l16]; pack 4 consecutive d -> 8B store
    size_t zrow = ((size_t)(b * SS + qb + 16 * w4 + l16)) * (HH * DHH) + h * DHH;
    #pragma unroll
    for (int mt = 0; mt < 4; mt++) {
        s16x4 pk;
        pk[0] = (short)f2bf(zacc[mt][0]);
        pk[1] = (short)f2bf(zacc[mt][1]);
        pk[2] = (short)f2bf(zacc[mt][2]);
        pk[3] = (short)f2bf(zacc[mt][3]);
        *reinterpret_cast<s16x4*>(z + zrow + 16 * mt + quad * 4) = pk;
    }
}

// ---------------- Kernel 3: output projection, 64x128 tile, dbuf DMA ----------
__device__ inline void stage128(unsigned short* dst, const unsigned short* src,
                                int w4, int l) {
    #pragma unroll
    for (int j = 0; j < 2; j++) {
        int eoff = (w4 * 2 + j) * 512;
        int e = eoff + l * 8;
        int row = e >> 5;
        int k8 = ((e >> 3) & 3) ^ ((row >> 1) & 3);
        __builtin_amdgcn_global_load_lds(AS1(src + (size_t)row * DD + k8 * 8),
                                         AS3(dst + eoff), 16, 0, 0);
    }
}
__device__ inline void stage64(unsigned short* dst, const unsigned short* src,
                               int w4, int l) {
    int eoff = w4 * 512;
    int e = eoff + l * 8;
    int row = e >> 5;
    int k8 = ((e >> 3) & 3) ^ ((row >> 1) & 3);
    __builtin_amdgcn_global_load_lds(AS1(src + (size_t)row * DD + k8 * 8),
                                     AS3(dst + eoff), 16, 0, 0);
}

__global__ __launch_bounds__(256) void out_gemm_kernel(
    const unsigned short* __restrict__ Z,
    const unsigned short* __restrict__ Wot,
    const float* __restrict__ bo,
    float* __restrict__ out)
{
    const int mt0 = blockIdx.x * 64;
    const int n0  = blockIdx.y * 128;
    const unsigned short* A = Z + (size_t)mt0 * DD;
    const unsigned short* Bw = Wot + (size_t)n0 * DD;

    // As0[0,2048) Bs0[2048,6144) As1[6144,8192) Bs1[8192,12288)
    __shared__ unsigned short smem[12288];

    const int t = threadIdx.x;
    const int l = t & 63, w4 = t >> 6;
    const int l16 = l & 15, quad = l >> 4;
    const int swz = (l16 >> 1) & 3;

    f32x4 acc[8] = {};

    stage64 (smem,        A,  w4, l);
    stage128(smem + 2048, Bw, w4, l);

    for (int it = 0; it < 24; ++it) {
        unsigned short* Ac = smem + (it & 1) * 6144;
        unsigned short* Bc = Ac + 2048;
        __syncthreads();
        if (it < 23) {
            unsigned short* An = smem + ((it + 1) & 1) * 6144;
            stage64 (An,        A  + (it + 1) * 32, w4, l);
            stage128(An + 2048, Bw + (it + 1) * 32, w4, l);
        }
        bfrag af[4], bg[2];
        #pragma unroll
        for (int mi = 0; mi < 4; mi++)
            af[mi] = *reinterpret_cast<const bfrag*>(&Ac[(mi * 16 + l16) * 32 + ((quad ^ swz) * 8)]);
        #pragma unroll
        for (int ni = 0; ni < 2; ni++)
            bg[ni] = *reinterpret_cast<const bfrag*>(&Bc[(w4 * 32 + ni * 16 + l16) * 32 + ((quad ^ swz) * 8)]);
        #pragma unroll
        for (int mi = 0; mi < 4; mi++)
            #pragma unroll
            for (int ni = 0; ni < 2; ni++)
                acc[mi * 2 + ni] = __builtin_amdgcn_mfma_f32_16x16x32_bf16(af[mi], bg[ni], acc[mi * 2 + ni], 0, 0, 0);
    }

    #pragma unroll
    for (int ni = 0; ni < 2; ni++) {
        int n = n0 + w4 * 32 + ni * 16 + l16;
        float bv0 = bo[n];
        #pragma unroll
        for (int mi = 0; mi < 4; mi++)
            #pragma unroll
            for (int r = 0; r < 4; r++) {
                int m = mt0 + mi * 16 + quad * 4 + r;
                out[(size_t)m * DD + n] = acc[mi * 2 + ni][r] + bv0;
            }
    }
}

extern "C" void kernel_launch(void* const* d_in, const int* in_sizes, int n_in,
                              void* d_out, int out_size, void* d_ws, size_t ws_size,
                              hipStream_t stream) {
    const float* Xq = (const float*)d_in[0];
    const float* Xk = (const float*)d_in[1];
    const float* Xv = (const float*)d_in[2];
    const float* Wq = (const float*)d_in[3];
    const float* Wk = (const float*)d_in[4];
    const float* Wv = (const float*)d_in[5];
    const float* Wo = (const float*)d_in[6];
    const float* bq = (const float*)d_in[7];
    const float* bk = (const float*)d_in[8];
    const float* bv = (const float*)d_in[9];
    const float* bo = (const float*)d_in[10];
    float* out = (float*)d_out;

    const size_t seg = (size_t)BB * HH * SS * DHH;   // 3,145,728 bf16 elems
    unsigned short* q   = (unsigned short*)d_ws;
    unsigned short* k   = q + seg;
    unsigned short* v   = k + seg;
    unsigned short* z   = v + seg;
    unsigned short* Wt  = z + seg;                    // 3*768*768
    unsigned short* Wot = Wt + (size_t)3 * DD * DD;   // 768*768
    float2* rope = (float2*)(Wot + (size_t)DD * DD);  // 2048*32 float2
    unsigned short* Xbf = (unsigned short*)(rope + 2048 * 32); // 3*4096*768

    pack_kernel<<<dim3(3136), 256, 0, stream>>>(Xq, Xk, Xv, Wq, Wk, Wv, Wo, Wt, Wot, rope, Xbf);
    qkv_gemm_kernel<<<dim3(MM / 64, DD / 128, 3), 256, 0, stream>>>(
        Xbf, Wt, bq, bk, bv, rope, q, k, v);
    attn_kernel<<<dim3(SS / 64, HH, BB), 256, 0, stream>>>(q, k, v, z);
    out_gemm_kernel<<<dim3(MM / 64, DD / 128), 256, 0, stream>>>(z, Wot, bo, out);
}

// Round 5
// 164.428 us; speedup vs baseline: 1.3509x; 1.0278x over previous
//
#include <hip/hip_runtime.h>
#include <hip/hip_bf16.h>

#define BB 2
#define SS 2048
#define DD 768
#define HH 12
#define DHH 64
#define WIN 128
#define MM (BB*SS)

typedef __attribute__((ext_vector_type(8))) short bfrag;
typedef __attribute__((ext_vector_type(4))) float f32x4;
typedef __attribute__((ext_vector_type(4))) short s16x4;

#define AS3(p) ((__attribute__((address_space(3))) void*)(p))
#define AS1(p) ((const __attribute__((address_space(1))) void*)(p))

__device__ inline unsigned short f2bf(float f) {
    union { __hip_bfloat16 h; unsigned short u; } cv;
    cv.h = __float2bfloat16(f);
    return cv.u;
}

// Stage a R x 32 bf16 tile (row-major, global stride DD) into LDS via DMA,
// 16B chunks XOR-swizzled: chunk cs at row goes to slot cs ^ ((row>>1)&3).
__device__ inline void stage128(unsigned short* dst, const unsigned short* src,
                                int w4, int l) {
    #pragma unroll
    for (int j = 0; j < 2; j++) {
        int eoff = (w4 * 2 + j) * 512;
        int e = eoff + l * 8;
        int row = e >> 5;
        int k8 = ((e >> 3) & 3) ^ ((row >> 1) & 3);
        __builtin_amdgcn_global_load_lds(AS1(src + (size_t)row * DD + k8 * 8),
                                         AS3(dst + eoff), 16, 0, 0);
    }
}
__device__ inline void stage64(unsigned short* dst, const unsigned short* src,
                               int w4, int l) {
    int eoff = w4 * 512;
    int e = eoff + l * 8;
    int row = e >> 5;
    int k8 = ((e >> 3) & 3) ^ ((row >> 1) & 3);
    __builtin_amdgcn_global_load_lds(AS1(src + (size_t)row * DD + k8 * 8),
                                     AS3(dst + eoff), 16, 0, 0);
}

// ---------------- Kernel 0: pack ----------------
__global__ __launch_bounds__(256) void pack_kernel(
    const float* __restrict__ Xq, const float* __restrict__ Xk, const float* __restrict__ Xv,
    const float* __restrict__ Wq, const float* __restrict__ Wk, const float* __restrict__ Wv,
    const float* __restrict__ Wo,
    unsigned short* __restrict__ Wt, unsigned short* __restrict__ Wot,
    float2* __restrict__ rope, unsigned short* __restrict__ Xbf)
{
    __shared__ float T[64][65];
    const int bid = blockIdx.x, t = threadIdx.x;
    if (bid < 432) {
        int proj = bid / 144, rem = bid % 144;
        int h = rem / 12, d0 = (rem % 12) * 64;
        const float* src = (proj == 0 ? Wq : (proj == 1 ? Wk : Wv)) + (size_t)h * DD * DHH;
        int row = t >> 2, c0 = (t & 3) * 16;
        const float4* p4 = reinterpret_cast<const float4*>(src + (size_t)(d0 + row) * DHH + c0);
        float4 x0 = p4[0], x1 = p4[1], x2 = p4[2], x3 = p4[3];
        float* tr = &T[row][c0];
        tr[0]=x0.x; tr[1]=x0.y; tr[2]=x0.z; tr[3]=x0.w;
        tr[4]=x1.x; tr[5]=x1.y; tr[6]=x1.z; tr[7]=x1.w;
        tr[8]=x2.x; tr[9]=x2.y; tr[10]=x2.z; tr[11]=x2.w;
        tr[12]=x3.x; tr[13]=x3.y; tr[14]=x3.z; tr[15]=x3.w;
        __syncthreads();
        int dh = t >> 2;
        unsigned short tmp[16];
        #pragma unroll
        for (int j = 0; j < 16; j++) tmp[j] = f2bf(T[c0 + j][dh]);
        unsigned short* dst = Wt + (size_t)proj * DD * DD + (size_t)(h * 64 + dh) * DD + d0 + c0;
        *reinterpret_cast<bfrag*>(dst)     = *reinterpret_cast<bfrag*>(tmp);
        *reinterpret_cast<bfrag*>(dst + 8) = *reinterpret_cast<bfrag*>(tmp + 8);
    } else if (bid < 576) {
        int id2 = bid - 432;
        int k0 = (id2 / 12) * 64, n0 = (id2 % 12) * 64;
        int row = t >> 2, c0 = (t & 3) * 16;
        const float4* p4 = reinterpret_cast<const float4*>(Wo + (size_t)(k0 + row) * DD + n0 + c0);
        float4 x0 = p4[0], x1 = p4[1], x2 = p4[2], x3 = p4[3];
        float* tr = &T[row][c0];
        tr[0]=x0.x; tr[1]=x0.y; tr[2]=x0.z; tr[3]=x0.w;
        tr[4]=x1.x; tr[5]=x1.y; tr[6]=x1.z; tr[7]=x1.w;
        tr[8]=x2.x; tr[9]=x2.y; tr[10]=x2.z; tr[11]=x2.w;
        tr[12]=x3.x; tr[13]=x3.y; tr[14]=x3.z; tr[15]=x3.w;
        __syncthreads();
        int nr = t >> 2;
        unsigned short tmp[16];
        #pragma unroll
        for (int j = 0; j < 16; j++) tmp[j] = f2bf(T[c0 + j][nr]);
        unsigned short* dst = Wot + (size_t)(n0 + nr) * DD + k0 + c0;
        *reinterpret_cast<bfrag*>(dst)     = *reinterpret_cast<bfrag*>(tmp);
        *reinterpret_cast<bfrag*>(dst + 8) = *reinterpret_cast<bfrag*>(tmp + 8);
    } else if (bid < 832) {
        int idx = (bid - 576) * 256 + t;   // p in [0,2048), i2 in [0,32)
        int p = idx >> 5, i2 = idx & 31;
        float inv_freq = exp2f(-(float)i2 * (13.287712379549449f / 32.0f));
        float s, c;
        sincosf((float)p * inv_freq, &s, &c);
        rope[idx] = make_float2(s, c);
    } else {
        int i = bid - 832;                  // 2304 blocks x 4096 elems
        int proj = i / 768;
        size_t off = (size_t)(i % 768) * 4096 + t * 16;
        const float* src = (proj == 0 ? Xq : (proj == 1 ? Xk : Xv)) + off;
        const float4* p4 = reinterpret_cast<const float4*>(src);
        float4 a0 = p4[0], a1 = p4[1], a2 = p4[2], a3 = p4[3];
        unsigned short u[16];
        u[0]=f2bf(a0.x); u[1]=f2bf(a0.y); u[2]=f2bf(a0.z); u[3]=f2bf(a0.w);
        u[4]=f2bf(a1.x); u[5]=f2bf(a1.y); u[6]=f2bf(a1.z); u[7]=f2bf(a1.w);
        u[8]=f2bf(a2.x); u[9]=f2bf(a2.y); u[10]=f2bf(a2.z); u[11]=f2bf(a2.w);
        u[12]=f2bf(a3.x); u[13]=f2bf(a3.y); u[14]=f2bf(a3.z); u[15]=f2bf(a3.w);
        unsigned short* dst = Xbf + (size_t)proj * MM * DD + off;
        *reinterpret_cast<bfrag*>(dst)     = *reinterpret_cast<bfrag*>(u);
        *reinterpret_cast<bfrag*>(dst + 8) = *reinterpret_cast<bfrag*>(u + 8);
    }
}

// ---------------- Kernel 1: QKV GEMM 128x128 (dbuf DMA) + bias + RoPE ----------
// (round-3 verified kernel: 576 blocks, 4 blocks/CU, 16 MFMA/wave/iter)
__global__ __launch_bounds__(256) void qkv_gemm_kernel(
    const unsigned short* __restrict__ Xbf,
    const unsigned short* __restrict__ Wt,
    const float* __restrict__ bq, const float* __restrict__ bk, const float* __restrict__ bv,
    const float2* __restrict__ rope,
    unsigned short* __restrict__ qo, unsigned short* __restrict__ ko, unsigned short* __restrict__ vo)
{
    const int mt0  = blockIdx.x * 128;
    const int n0   = blockIdx.y * 128;
    const int proj = blockIdx.z;
    const unsigned short* X = Xbf + (size_t)proj * MM * DD + (size_t)mt0 * DD;
    const unsigned short* W = Wt + (size_t)proj * DD * DD + (size_t)n0 * DD;
    const float* bias = proj == 0 ? bq : (proj == 1 ? bk : bv);

    __shared__ unsigned short smem[128 * 140];

    const int t = threadIdx.x;
    const int l = t & 63, w4 = t >> 6;
    const int l16 = l & 15, quad = l >> 4;
    const int wr = w4 >> 1, wc = w4 & 1;
    const int swz = (l16 >> 1) & 3;

    f32x4 acc[16] = {};

    stage128(smem,        X, w4, l);
    stage128(smem + 4096, W, w4, l);

    for (int it = 0; it < 24; ++it) {
        unsigned short* Ac = smem + (it & 1) * 8192;
        unsigned short* Bc = Ac + 4096;
        __syncthreads();
        if (it < 23) {
            unsigned short* An = smem + ((it + 1) & 1) * 8192;
            stage128(An,        X + (it + 1) * 32, w4, l);
            stage128(An + 4096, W + (it + 1) * 32, w4, l);
        }
        bfrag af[4], bg[4];
        #pragma unroll
        for (int mi = 0; mi < 4; mi++)
            af[mi] = *reinterpret_cast<const bfrag*>(&Ac[(wr * 64 + mi * 16 + l16) * 32 + ((quad ^ swz) * 8)]);
        #pragma unroll
        for (int ni = 0; ni < 4; ni++)
            bg[ni] = *reinterpret_cast<const bfrag*>(&Bc[(wc * 64 + ni * 16 + l16) * 32 + ((quad ^ swz) * 8)]);
        #pragma unroll
        for (int mi = 0; mi < 4; mi++)
            #pragma unroll
            for (int ni = 0; ni < 4; ni++)
                acc[mi * 4 + ni] = __builtin_amdgcn_mfma_f32_16x16x32_bf16(af[mi], bg[ni], acc[mi * 4 + ni], 0, 0, 0);
    }
    __syncthreads();

    unsigned short* Ct = smem;   // stride 140
    const int b = mt0 >> 11;
    if (proj < 2) {
        #pragma unroll
        for (int ni = 0; ni < 4; ni++) {
            int nloc = wc * 64 + ni * 16 + l16;
            int n = n0 + nloc;
            int dh = n & 63;
            float bv0 = bias[n];
            float bv1 = bias[n ^ 32];
            float sgn = (dh & 32) ? 1.0f : -1.0f;
            const float2* rp = rope + (dh & 31);
            #pragma unroll
            for (int mi = 0; mi < 4; mi++)
                #pragma unroll
                for (int r = 0; r < 4; r++) {
                    int ploc = wr * 64 + mi * 16 + quad * 4 + r;
                    int p = (mt0 + ploc) & (SS - 1);
                    float2 sc = rp[p << 5];
                    float val = acc[mi * 4 + ni][r] + bv0;
                    float pr  = acc[mi * 4 + (ni ^ 2)][r] + bv1;
                    Ct[ploc * 140 + nloc] = f2bf(val * sc.y + sgn * pr * sc.x);
                }
        }
        __syncthreads();
        unsigned short* dst = (proj == 0) ? qo : ko;
        #pragma unroll
        for (int jj = 0; jj < 8; jj++) {
            int id = jj * 256 + t;
            int row = id >> 4, c = (id & 15) * 8;
            int n = n0 + c, h = n >> 6, dh = n & 63;
            int p = (mt0 + row) & (SS - 1);
            bfrag vv = *reinterpret_cast<const bfrag*>(&Ct[row * 140 + c]);
            *reinterpret_cast<bfrag*>(dst + (((size_t)(b * HH + h) * SS + p) << 6) + dh) = vv;
        }
    } else {
        #pragma unroll
        for (int ni = 0; ni < 4; ni++) {
            int nloc = wc * 64 + ni * 16 + l16;
            float bv0 = bias[n0 + nloc];
            #pragma unroll
            for (int mi = 0; mi < 4; mi++)
                #pragma unroll
                for (int r = 0; r < 4; r++) {
                    int ploc = wr * 64 + mi * 16 + quad * 4 + r;
                    Ct[nloc * 140 + ploc] = f2bf(acc[mi * 4 + ni][r] + bv0);
                }
        }
        __syncthreads();
        int p0 = mt0 & (SS - 1);
        #pragma unroll
        for (int jj = 0; jj < 8; jj++) {
            int id = jj * 256 + t;
            int row = id >> 4, c = (id & 15) * 8;
            int n = n0 + row, h = n >> 6, dh = n & 63;
            bfrag vv = *reinterpret_cast<const bfrag*>(&Ct[row * 140 + c]);
            *reinterpret_cast<bfrag*>(vo + (((size_t)(b * HH + h) * DHH + dh) << 11) + p0 + c) = vv;
        }
    }
}

// ---------------- Kernel 2: sliding-window attention, K and V both DMA->LDS ----
// grid (S/64, H, B) = 768 blocks; LDS 49KB -> 3 blocks/CU -> whole grid
// co-resident. VGPR ~110 (no V fragments held across softmax).
__global__ __launch_bounds__(256) void attn_kernel(
    const unsigned short* __restrict__ q,
    const unsigned short* __restrict__ k,
    const unsigned short* __restrict__ v,
    unsigned short* __restrict__ z)
{
    const int qb = blockIdx.x * 64;
    const int h  = blockIdx.y;
    const int b  = blockIdx.z;
    const int kb = qb - WIN;   // may be negative: reads land in prior ws slab (masked)

    // K panels [0,12288); P aliases [0,12800); Vt [12800,25088)
    __shared__ unsigned short sA[25088];

    const int t = threadIdx.x;
    const int w4 = t >> 6, l = t & 63;
    const int l16 = l & 15, quad = l >> 4;
    const int swz = (l16 >> 1) & 3;

    const size_t qkbase = (size_t)(b * HH + h) * SS * DHH;
    const unsigned short* kp = (k + qkbase) + (ptrdiff_t)kb * DHH;
    const unsigned short* vp = (v + (size_t)(b * HH + h) * DHH * SS) + (ptrdiff_t)kb;

    // --- stage K: 6 panels (64 rows x 32 cols), 24 DMA groups, 6 per wave ---
    #pragma unroll
    for (int j = 0; j < 6; j++) {
        int g = w4 * 6 + j;
        int panel = g >> 2, sub = g & 3;
        int rg = panel >> 1, kpart = panel & 1;
        int e = sub * 512 + l * 8;
        int row = e >> 5;
        int k8 = ((e >> 3) & 3) ^ ((row >> 1) & 3);
        __builtin_amdgcn_global_load_lds(
            AS1(kp + (size_t)(rg * 64 + row) * DHH + kpart * 32 + k8 * 8),
            AS3(sA + panel * 2048 + sub * 512), 16, 0, 0);
    }
    // --- stage V^T: Vt[d=64][c=192], chunk-swizzled s = cs ^ (d&7); 24 groups ---
    #pragma unroll
    for (int j = 0; j < 6; j++) {
        int g = w4 * 6 + j;
        int F = g * 64 + l;               // flat 16B-chunk id, 0..1535
        int d = F / 24, s = F % 24;
        int cs = s ^ (d & 7);             // source chunk for this slot
        __builtin_amdgcn_global_load_lds(
            AS1(vp + (size_t)d * SS + cs * 8),
            AS3(sA + 12800 + g * 512), 16, 0, 0);
    }
    // --- Q fragments direct from global (A-layout: contiguous 8 bf16/lane) ---
    bfrag qf[2];
    #pragma unroll
    for (int kk = 0; kk < 2; kk++)
        qf[kk] = *reinterpret_cast<const bfrag*>(
            q + qkbase + (size_t)(qb + 16 * w4 + l16) * DHH + kk * 32 + quad * 8);

    __syncthreads();   // K + V resident

    // --- QK^T: S[q=16*w4+quad*4+r][key=16*mt+l16] ---
    f32x4 sacc[12] = {};
    #pragma unroll
    for (int kk = 0; kk < 2; kk++)
        #pragma unroll
        for (int mt = 0; mt < 12; mt++) {
            int kr = 16 * mt + l16;
            bfrag bf = *reinterpret_cast<const bfrag*>(
                &sA[(((kr >> 6) * 2 + kk) * 2048) + (kr & 63) * 32 + ((quad ^ swz) * 8)]);
            sacc[mt] = __builtin_amdgcn_mfma_f32_16x16x32_bf16(qf[kk], bf, sacc[mt], 0, 0, 0);
        }

    // --- mask + scale + exact softmax ---
    float mx[4] = {-3e38f, -3e38f, -3e38f, -3e38f};
    #pragma unroll
    for (int mt = 0; mt < 12; mt++)
        #pragma unroll
        for (int r = 0; r < 4; r++) {
            int row = 16 * w4 + quad * 4 + r;
            int c = 16 * mt + l16;
            bool valid = (c > row) && (c <= row + WIN) && (kb + c >= 0);
            float s = valid ? sacc[mt][r] * 0.125f : -3e38f;
            sacc[mt][r] = s;
            mx[r] = fmaxf(mx[r], s);
        }
    #pragma unroll
    for (int off = 1; off < 16; off <<= 1)
        #pragma unroll
        for (int r = 0; r < 4; r++) mx[r] = fmaxf(mx[r], __shfl_xor(mx[r], off, 64));
    float sum[4] = {0.f, 0.f, 0.f, 0.f};
    #pragma unroll
    for (int mt = 0; mt < 12; mt++)
        #pragma unroll
        for (int r = 0; r < 4; r++) {
            float p = __expf(sacc[mt][r] - mx[r]);
            sacc[mt][r] = p;
            sum[r] += p;
        }
    #pragma unroll
    for (int off = 1; off < 16; off <<= 1)
        #pragma unroll
        for (int r = 0; r < 4; r++) sum[r] += __shfl_xor(sum[r], off, 64);
    float inv[4];
    #pragma unroll
    for (int r = 0; r < 4; r++) inv[r] = 1.0f / sum[r];

    __syncthreads();   // all K reads done before P overwrites that region

    // --- P -> LDS (row-major stride 200); each wave touches only its own
    //     16-row strip (write pattern == read pattern) -> no barrier after ---
    unsigned short* Ps = sA;
    #pragma unroll
    for (int mt = 0; mt < 12; mt++)
        #pragma unroll
        for (int r = 0; r < 4; r++)
            Ps[(16 * w4 + quad * 4 + r) * 200 + 16 * mt + l16] = f2bf(sacc[mt][r] * inv[r]);

    // --- PV as Z^T = V^T(A) . P^T(B) ---
    unsigned short* Vt = sA + 12800;
    f32x4 zacc[4] = {};
    #pragma unroll
    for (int ci = 0; ci < 6; ci++) {
        bfrag pb = *reinterpret_cast<const bfrag*>(
            &Ps[(16 * w4 + l16) * 200 + ci * 32 + quad * 8]);
        #pragma unroll
        for (int mt = 0; mt < 4; mt++) {
            int d = 16 * mt + l16;
            bfrag va = *reinterpret_cast<const bfrag*>(
                &Vt[d * 192 + (((ci * 4 + quad) ^ (l16 & 7)) * 8)]);
            zacc[mt] = __builtin_amdgcn_mfma_f32_16x16x32_bf16(va, pb, zacc[mt], 0, 0, 0);
        }
    }
    // lane holds Zt[d=16*mt+quad*4+r][q=16*w4+l16]; 4 consecutive d -> 8B store
    size_t zrow = ((size_t)(b * SS + qb + 16 * w4 + l16)) * (HH * DHH) + h * DHH;
    #pragma unroll
    for (int mt = 0; mt < 4; mt++) {
        s16x4 pk;
        pk[0] = (short)f2bf(zacc[mt][0]);
        pk[1] = (short)f2bf(zacc[mt][1]);
        pk[2] = (short)f2bf(zacc[mt][2]);
        pk[3] = (short)f2bf(zacc[mt][3]);
        *reinterpret_cast<s16x4*>(z + zrow + 16 * mt + quad * 4) = pk;
    }
}

// ---------------- Kernel 3: output projection, 64x128 tile, dbuf DMA ----------
__global__ __launch_bounds__(256) void out_gemm_kernel(
    const unsigned short* __restrict__ Z,
    const unsigned short* __restrict__ Wot,
    const float* __restrict__ bo,
    float* __restrict__ out)
{
    const int mt0 = blockIdx.x * 64;
    const int n0  = blockIdx.y * 128;
    const unsigned short* A = Z + (size_t)mt0 * DD;
    const unsigned short* Bw = Wot + (size_t)n0 * DD;

    __shared__ unsigned short smem[12288];

    const int t = threadIdx.x;
    const int l = t & 63, w4 = t >> 6;
    const int l16 = l & 15, quad = l >> 4;
    const int swz = (l16 >> 1) & 3;

    f32x4 acc[8] = {};

    stage64 (smem,        A,  w4, l);
    stage128(smem + 2048, Bw, w4, l);

    for (int it = 0; it < 24; ++it) {
        unsigned short* Ac = smem + (it & 1) * 6144;
        unsigned short* Bc = Ac + 2048;
        __syncthreads();
        if (it < 23) {
            unsigned short* An = smem + ((it + 1) & 1) * 6144;
            stage64 (An,        A  + (it + 1) * 32, w4, l);
            stage128(An + 2048, Bw + (it + 1) * 32, w4, l);
        }
        bfrag af[4], bg[2];
        #pragma unroll
        for (int mi = 0; mi < 4; mi++)
            af[mi] = *reinterpret_cast<const bfrag*>(&Ac[(mi * 16 + l16) * 32 + ((quad ^ swz) * 8)]);
        #pragma unroll
        for (int ni = 0; ni < 2; ni++)
            bg[ni] = *reinterpret_cast<const bfrag*>(&Bc[(w4 * 32 + ni * 16 + l16) * 32 + ((quad ^ swz) * 8)]);
        #pragma unroll
        for (int mi = 0; mi < 4; mi++)
            #pragma unroll
            for (int ni = 0; ni < 2; ni++)
                acc[mi * 2 + ni] = __builtin_amdgcn_mfma_f32_16x16x32_bf16(af[mi], bg[ni], acc[mi * 2 + ni], 0, 0, 0);
    }

    #pragma unroll
    for (int ni = 0; ni < 2; ni++) {
        int n = n0 + w4 * 32 + ni * 16 + l16;
        float bv0 = bo[n];
        #pragma unroll
        for (int mi = 0; mi < 4; mi++)
            #pragma unroll
            for (int r = 0; r < 4; r++) {
                int m = mt0 + mi * 16 + quad * 4 + r;
                out[(size_t)m * DD + n] = acc[mi * 2 + ni][r] + bv0;
            }
    }
}

extern "C" void kernel_launch(void* const* d_in, const int* in_sizes, int n_in,
                              void* d_out, int out_size, void* d_ws, size_t ws_size,
                              hipStream_t stream) {
    const float* Xq = (const float*)d_in[0];
    const float* Xk = (const float*)d_in[1];
    const float* Xv = (const float*)d_in[2];
    const float* Wq = (const float*)d_in[3];
    const float* Wk = (const float*)d_in[4];
    const float* Wv = (const float*)d_in[5];
    const float* Wo = (const float*)d_in[6];
    const float* bq = (const float*)d_in[7];
    const float* bk = (const float*)d_in[8];
    const float* bv = (const float*)d_in[9];
    const float* bo = (const float*)d_in[10];
    float* out = (float*)d_out;

    const size_t seg = (size_t)BB * HH * SS * DHH;   // 3,145,728 bf16 elems
    unsigned short* q   = (unsigned short*)d_ws;
    unsigned short* k   = q + seg;
    unsigned short* v   = k + seg;
    unsigned short* z   = v + seg;
    unsigned short* Wt  = z + seg;                    // 3*768*768
    unsigned short* Wot = Wt + (size_t)3 * DD * DD;   // 768*768
    float2* rope = (float2*)(Wot + (size_t)DD * DD);  // 2048*32 float2
    unsigned short* Xbf = (unsigned short*)(rope + 2048 * 32); // 3*4096*768

    pack_kernel<<<dim3(3136), 256, 0, stream>>>(Xq, Xk, Xv, Wq, Wk, Wv, Wo, Wt, Wot, rope, Xbf);
    qkv_gemm_kernel<<<dim3(MM / 128, DD / 128, 3), 256, 0, stream>>>(
        Xbf, Wt, bq, bk, bv, rope, q, k, v);
    attn_kernel<<<dim3(SS / 64, HH, BB), 256, 0, stream>>>(q, k, v, z);
    out_gemm_kernel<<<dim3(MM / 64, DD / 128), 256, 0, stream>>>(z, Wot, bo, out);
}